// Round 13
// baseline (104.407 us; speedup 1.0000x reference)
//
#include <hip/hip_runtime.h>
#include <hip/hip_bf16.h>
#include <hip/hip_cooperative_groups.h>

namespace cg = cooperative_groups;

#define S_LEN 4096
#define DIM   128
#define NB    4
#define L_CHUNK 128
#define NCH   (S_LEN / L_CHUNK)      // 32 chunks per batch
#define NHC   (2 * NCH)              // 64 half-chunks per batch
#define ROPE_BLKS (NB * S_LEN / 4)   // fallback prep blocks
#define TR_BLKS   (NB * S_LEN / 64)
#define NQT   (S_LEN / 256)          // fallback: 16 q-tiles per batch
#define CH_FB 3                      // fallback split-K

typedef __bf16 bf16_t;
typedef __attribute__((ext_vector_type(4)))  float        f32x4;
typedef __attribute__((ext_vector_type(8)))  __bf16       bf16x8;
typedef __attribute__((ext_vector_type(16))) float        f32x16;
typedef __attribute__((ext_vector_type(4)))  unsigned int u32x4;

#define MFMA32(a, b, c) __builtin_amdgcn_mfma_f32_32x32x16_bf16((a), (b), (c), 0, 0, 0)
#define CVTPK(d, a, b) asm("v_cvt_pk_bf16_f32 %0, %1, %2" : "=v"(d) : "v"(a), "v"(b))
// vdst HIGH lanes <-> vsrc LOW lanes (verified round 2)
#define PSWAP(d, s)    asm("v_permlane32_swap_b32 %0, %1" : "+v"(d), "+v"(s))

__device__ __forceinline__ unsigned swzo(int row, int colByte) {
    // 256B rows
    return (unsigned)(row * 256 + (colByte ^ ((row & 15) << 4)));
}
__device__ __forceinline__ unsigned swz64(int row, int colByte) {
    // 128B rows (64 bf16 per row)
    return (unsigned)(row * 128 + (colByte ^ ((row & 7) << 4)));
}

__device__ __forceinline__ void cvt_swap(const f32x16& s, unsigned int w[8]) {
    CVTPK(w[0], s[0],  s[1]);  CVTPK(w[1], s[2],  s[3]);
    CVTPK(w[2], s[4],  s[5]);  CVTPK(w[3], s[6],  s[7]);
    CVTPK(w[4], s[8],  s[9]);  CVTPK(w[5], s[10], s[11]);
    CVTPK(w[6], s[12], s[13]); CVTPK(w[7], s[14], s[15]);
    PSWAP(w[0], w[2]); PSWAP(w[1], w[3]);
    PSWAP(w[4], w[6]); PSWAP(w[5], w[7]);
}

// ============ fused cooperative kernel: prep+stage1 | scan | stage3 ============
// grid = NB*NHC = 256 blocks x 256 threads, co-resident (1+/CU), lb(256,1)
// (PSWAP curse rule: phase 3 has the cvt/permlane cluster -> never lb>=2).
__launch_bounds__(256, 1)
__global__ void fused_all_kernel(const float* __restrict__ Q,
                                 const float* __restrict__ K,
                                 const float* __restrict__ V,
                                 bf16_t* __restrict__ Qr,
                                 bf16_t* __restrict__ Kr,
                                 bf16_t* __restrict__ Vt,
                                 bf16_t* __restrict__ Gh,
                                 bf16_t* __restrict__ Gp,
                                 float* __restrict__ Out) {
    __shared__ char smem[49152];   // phase1: KsT16K+VsT16K ; phase3: Ks32K+Vs16K
    cg::grid_group grid = cg::this_grid();

    int bid = blockIdx.x;
    int tid = threadIdx.x, w = tid >> 6, lane = tid & 63;
    int lr = lane & 31, lg = lane >> 5;

    // ================= phase 1: rope + transpose-stage + G_half =================
    {
        bf16_t* KsT = (bf16_t*)smem;            // [dk][k_loc] swz64
        bf16_t* VsT = (bf16_t*)(smem + 16384);  // [dv][k_loc] swz64
        int b  = bid >> 6;
        int hc = bid & 63;
        int k0 = hc * 64;
        {
            int srow = tid >> 2;                 // 0..63 local row
            int j    = tid & 3;                  // col quarter
            int s    = k0 + srow;
            size_t base = ((size_t)b * S_LEN + s) * DIM;
            f32x4 ql[4], qh[4], kl[4], vl[4], vh[4], kh[4];
            #pragma unroll
            for (int u = 0; u < 4; ++u) {
                ql[u] = *(const f32x4*)(Q + base + 16 * j + 4 * u);
                qh[u] = *(const f32x4*)(Q + base + 64 + 16 * j + 4 * u);
                kl[u] = *(const f32x4*)(K + base + 16 * j + 4 * u);
                kh[u] = *(const f32x4*)(K + base + 64 + 16 * j + 4 * u);
                vl[u] = *(const f32x4*)(V + base + 16 * j + 4 * u);
                vh[u] = *(const f32x4*)(V + base + 64 + 16 * j + 4 * u);
            }
            bf16_t oql[16], oqh[16], okl[16], okh[16];
            #pragma unroll
            for (int e = 0; e < 16; ++e) {
                int i = 16 * j + e;
                float ex      = -(float)i * (13.287712379549449f / 64.0f);
                float inv_rev = exp2f(ex) * 0.15915494309189535f;
                float rev = (float)s * inv_rev;
                float fr  = rev - floorf(rev);
                float c  = __builtin_amdgcn_cosf(fr);
                float sn = __builtin_amdgcn_sinf(fr);
                float q1 = ql[e >> 2][e & 3], q2 = qh[e >> 2][e & 3];
                float k1 = kl[e >> 2][e & 3], k2 = kh[e >> 2][e & 3];
                oql[e] = (bf16_t)(q1 * c - q2 * sn);
                oqh[e] = (bf16_t)(q2 * c + q1 * sn);
                okl[e] = (bf16_t)(k1 * c - k2 * sn);
                okh[e] = (bf16_t)(k2 * c + k1 * sn);
            }
            #pragma unroll
            for (int hlf = 0; hlf < 2; ++hlf) {
                *(bf16x8*)(Qr + base + 16 * j + 8 * hlf)      = *(bf16x8*)&oql[8 * hlf];
                *(bf16x8*)(Qr + base + 64 + 16 * j + 8 * hlf) = *(bf16x8*)&oqh[8 * hlf];
                *(bf16x8*)(Kr + base + 16 * j + 8 * hlf)      = *(bf16x8*)&okl[8 * hlf];
                *(bf16x8*)(Kr + base + 64 + 16 * j + 8 * hlf) = *(bf16x8*)&okh[8 * hlf];
            }
            #pragma unroll
            for (int e = 0; e < 16; ++e) {
                int dk = 16 * j + e;
                *(bf16_t*)((char*)KsT + swz64(dk,      srow * 2)) = okl[e];
                *(bf16_t*)((char*)KsT + swz64(dk + 64, srow * 2)) = okh[e];
                *(bf16_t*)((char*)VsT + swz64(dk,      srow * 2)) = (bf16_t)vl[e >> 2][e & 3];
                *(bf16_t*)((char*)VsT + swz64(dk + 64, srow * 2)) = (bf16_t)vh[e >> 2][e & 3];
            }
        }
        __syncthreads();

        f32x16 acc[4];
        #pragma unroll
        for (int db = 0; db < 4; ++db)
            #pragma unroll
            for (int r = 0; r < 16; ++r) acc[db][r] = 0.f;

        #pragma unroll
        for (int sI = 0; sI < 4; ++sI) {
            bf16x8 af = *(const bf16x8*)((const char*)VsT +
                swz64(32 * w + lr, (sI * 16 + lg * 8) * 2));
            #pragma unroll
            for (int db = 0; db < 4; ++db) {
                bf16x8 bfr = *(const bf16x8*)((const char*)KsT +
                    swz64(32 * db + lr, (sI * 16 + lg * 8) * 2));
                acc[db] = MFMA32(af, bfr, acc[db]);
            }
        }
        bf16_t* Gc = Gh + ((size_t)b * NHC + hc) * DIM * DIM;
        #pragma unroll
        for (int db = 0; db < 4; ++db)
            #pragma unroll
            for (int r = 0; r < 16; ++r) {
                int dv = 32 * w + (r & 3) + ((r >> 2) << 3) + (lg << 2);
                Gc[(size_t)dv * DIM + 32 * db + lr] = (bf16_t)acc[db][r];
            }

        #pragma unroll
        for (int m = 0; m < 4; ++m) {
            int idx  = tid + 256 * m;            // 0..1023
            int dv   = idx >> 3;
            int slot = idx & 7;
            bf16x8 v = *(const bf16x8*)((const char*)VsT + swz64(dv, slot * 16));
            *(bf16x8*)(Vt + ((size_t)b * DIM + dv) * S_LEN + k0 + slot * 8) = v;
        }
    }

    grid.sync();

    // ================= phase 2: exclusive prefix scan Gh -> Gp =================
    {
        int col = bid * 256 + tid;               // [0, 65536) = NB * DIM * DIM
        int b   = col >> 14;
        int p   = col & 16383;
        const bf16_t* ph = Gh + (size_t)b * NHC * DIM * DIM + p;
        bf16_t* pp = Gp + (size_t)b * NCH * DIM * DIM + p;
        float run = 0.f;
        #pragma unroll
        for (int c = 0; c < NCH; ++c) {
            pp[(size_t)c * DIM * DIM] = (bf16_t)run;
            run += (float)ph[(size_t)(2 * c) * DIM * DIM] +
                   (float)ph[(size_t)(2 * c + 1) * DIM * DIM];
        }
    }

    grid.sync();

    // ================= phase 3: O = Q*Gp + tril(Q Kc^T) Vc =================
    {
        bf16_t* Ks = (bf16_t*)smem;             // 32 KB [k][d] swzo
        bf16_t* Vs = (bf16_t*)(smem + 32768);   // 16 KB [dv-local][k] swzo
        int b  = bid >> 6;
        int c  = (bid >> 1) & 31;
        int dh = bid & 1;
        int q0 = c * L_CHUNK;
        const bf16_t* Qb = Qr + (size_t)b * S_LEN * DIM;
        const bf16_t* Kb = Kr + (size_t)b * S_LEN * DIM;
        const bf16_t* Vb = Vt + (size_t)b * DIM * S_LEN;
        const bf16_t* Gb = Gp + ((size_t)b * NCH + c) * DIM * DIM;

        bf16x8 qf[8];
        #pragma unroll
        for (int s2 = 0; s2 < 8; ++s2)
            qf[s2] = *(const bf16x8*)(Qb + (size_t)(q0 + 32 * w + lr) * DIM
                                      + s2 * 16 + lg * 8);

        #pragma unroll
        for (int j = 0; j < 8; ++j) {
            int idx = tid + j * 256;
            int row = idx >> 4, slot = idx & 15;
            u32x4 kd = *(const u32x4*)(Kb + (size_t)(q0 + row) * DIM + slot * 8);
            *(u32x4*)((char*)Ks + swzo(row, slot * 16)) = kd;
        }
        #pragma unroll
        for (int j = 0; j < 4; ++j) {
            int idx = tid + j * 256;            // row in [0,64)
            int row = idx >> 4, slot = idx & 15;
            u32x4 vd = *(const u32x4*)(Vb + (size_t)(64 * dh + row) * S_LEN + q0 + slot * 8);
            *(u32x4*)((char*)Vs + swzo(row, slot * 16)) = vd;
        }
        __syncthreads();

        f32x16 acc[2];
        #pragma unroll
        for (int i = 0; i < 2; ++i)
            #pragma unroll
            for (int r = 0; r < 16; ++r) acc[i][r] = 0.f;

        if (c > 0) {
            #pragma unroll
            for (int s2 = 0; s2 < 8; ++s2) {
                #pragma unroll
                for (int i = 0; i < 2; ++i) {
                    bf16x8 gfr = *(const bf16x8*)(Gb +
                        (size_t)(64 * dh + 32 * i + lr) * DIM + s2 * 16 + lg * 8);
                    acc[i] = MFMA32(qf[s2], gfr, acc[i]);
                }
            }
        }

        for (int g = 0; g <= w; ++g) {
            int ksub = g * 32;
            f32x16 sa;
            #pragma unroll
            for (int r = 0; r < 16; ++r) sa[r] = 0.f;
            #pragma unroll
            for (int s2 = 0; s2 < 8; ++s2) {
                bf16x8 af = *(const bf16x8*)((const char*)Ks +
                    swzo(ksub + lr, (s2 * 16 + lg * 8) * 2));
                sa = MFMA32(af, qf[s2], sa);
            }
            if (g == w) {
                #pragma unroll
                for (int r = 0; r < 16; ++r) {
                    int crow = (r & 3) + ((r >> 2) << 3) + (lg << 2);
                    sa[r] = (crow > lr) ? 0.f : sa[r];
                }
            }
            unsigned int wv[8];
            cvt_swap(sa, wv);
            u32x4 tA = {wv[0], wv[1], wv[2], wv[3]};
            u32x4 tB = {wv[4], wv[5], wv[6], wv[7]};
            bf16x8 pA = __builtin_bit_cast(bf16x8, tA);
            bf16x8 pB = __builtin_bit_cast(bf16x8, tB);
            #pragma unroll
            for (int i = 0; i < 2; ++i) {
                bf16x8 v0 = *(const bf16x8*)((const char*)Vs +
                    swzo(32 * i + lr, (ksub + lg * 8) * 2));
                bf16x8 v1 = *(const bf16x8*)((const char*)Vs +
                    swzo(32 * i + lr, (ksub + 16 + lg * 8) * 2));
                acc[i] = MFMA32(pA, v0, acc[i]);
                acc[i] = MFMA32(pB, v1, acc[i]);
            }
        }

        float* Ob = Out + (size_t)b * S_LEN * DIM;
        #pragma unroll
        for (int i = 0; i < 2; ++i)
            #pragma unroll
            for (int r = 0; r < 16; ++r) {
                int q = q0 + 32 * w + (r & 3) + ((r >> 2) << 3) + (lg << 2);
                int d = 64 * dh + 32 * i + lr;
                Ob[(size_t)q * DIM + d] = acc[i][r];
            }
    }
}

// ---------------- fallback path (small ws): r2-verified prep + atomic kernel ----------------
__global__ void prep_fb_kernel(const float* __restrict__ Q,
                               const float* __restrict__ K,
                               const float* __restrict__ V,
                               bf16_t* __restrict__ Qr,
                               bf16_t* __restrict__ Kr,
                               bf16_t* __restrict__ Vt) {
    int bid = blockIdx.x;
    int t   = threadIdx.x;
    if (bid < ROPE_BLKS) {
        int i   = t & 63;
        int row = bid * 4 + (t >> 6);
        int s   = row & (S_LEN - 1);
        size_t base = (size_t)row * DIM;
        float e       = -(float)i * (13.287712379549449f / 64.0f);
        float inv_rev = exp2f(e) * 0.15915494309189535f;
        float rev = (float)s * inv_rev;
        float fr  = rev - floorf(rev);
        float c  = __builtin_amdgcn_cosf(fr);
        float sn = __builtin_amdgcn_sinf(fr);
        float q1 = Q[base + i], q2 = Q[base + i + 64];
        float k1 = K[base + i], k2 = K[base + i + 64];
        Qr[base + i]      = (bf16_t)(q1 * c - q2 * sn);
        Qr[base + i + 64] = (bf16_t)(q2 * c + q1 * sn);
        Kr[base + i]      = (bf16_t)(k1 * c - k2 * sn);
        Kr[base + i + 64] = (bf16_t)(k2 * c + k1 * sn);
    } else {
        int idx = bid - ROPE_BLKS;
        int b   = idx >> 6;
        int s0  = (idx & 63) * 64;
        int d   = t >> 1;
        int sh  = (t & 1) * 32;
        const float* vb = V + (size_t)b * S_LEN * DIM;
        bf16_t* ob = Vt + ((size_t)b * DIM + d) * S_LEN;
        #pragma unroll
        for (int j8 = 0; j8 < 4; ++j8) {
            bf16x8 u;
            #pragma unroll
            for (int e2 = 0; e2 < 8; ++e2) {
                int s = s0 + sh + j8 * 8 + e2;
                u[e2] = (bf16_t)vb[(size_t)s * DIM + d];
            }
            *(bf16x8*)(ob + s0 + sh + j8 * 8) = u;
        }
    }
}

__launch_bounds__(256, 2)
__global__ void attn_fb_kernel(const bf16_t* __restrict__ Qr,
                               const bf16_t* __restrict__ Kr,
                               const bf16_t* __restrict__ Vt,
                               float* __restrict__ Out) {
    __shared__ bf16_t Kt[128 * 128];
    __shared__ bf16_t Vl[128 * 128];
    int b = blockIdx.x & 3;
    int t = blockIdx.x >> 2;
    int qt = 0, c0 = 0;
    for (int i2 = NQT - 1; i2 >= 0; --i2) {
        int n = (2 * (i2 + 1) + CH_FB - 1) / CH_FB;
        if (t < n) { qt = i2; c0 = t; break; }
        t -= n;
    }
    int nkt   = 2 * (qt + 1);
    int kt_lo = c0 * CH_FB;
    int kt_hi = min(kt_lo + CH_FB, nkt);
    bool single = ((nkt + CH_FB - 1) / CH_FB) == 1;

    int tid = threadIdx.x, w = tid >> 6, lane = tid & 63;
    int lr = lane & 31, lg = lane >> 5;
    int qw = qt * 256 + w * 64;
    const bf16_t* Qb = Qr + (size_t)b * S_LEN * DIM;
    const bf16_t* Kb = Kr + (size_t)b * S_LEN * DIM;
    const bf16_t* Vb = Vt + (size_t)b * DIM * S_LEN;

    bf16x8 qf[2][8];
    #pragma unroll
    for (int qb = 0; qb < 2; ++qb)
        #pragma unroll
        for (int s2 = 0; s2 < 8; ++s2)
            qf[qb][s2] = *(const bf16x8*)(Qb + (size_t)(qw + qb * 32 + lr) * DIM
                                          + s2 * 16 + lg * 8);
    f32x16 acc[2][4];
    #pragma unroll
    for (int qb = 0; qb < 2; ++qb)
        #pragma unroll
        for (int db = 0; db < 4; ++db)
            #pragma unroll
            for (int r = 0; r < 16; ++r) acc[qb][db][r] = 0.f;

    for (int kt = kt_lo; kt < kt_hi; ++kt) {
        int kbase = kt * 128;
        #pragma unroll
        for (int j = 0; j < 8; ++j) {
            int idx = tid + j * 256;
            int row = idx >> 4, slot = idx & 15;
            u32x4 kd = *(const u32x4*)(Kb + (size_t)(kbase + row) * DIM + slot * 8);
            *(u32x4*)((char*)Kt + swzo(row, slot * 16)) = kd;
            u32x4 vd = *(const u32x4*)(Vb + (size_t)row * S_LEN + kbase + slot * 8);
            *(u32x4*)((char*)Vl + swzo(row, slot * 16)) = vd;
        }
        __syncthreads();
        #pragma unroll
        for (int kb = 0; kb < 4; ++kb) {
            int ksub = kb * 32;
            int kmin = kbase + ksub;
            if (kmin > qw + 63) break;
            bool do0 = (kmin <= qw + 31);
            f32x16 s0, s1;
            #pragma unroll
            for (int r = 0; r < 16; ++r) { s0[r] = 0.f; s1[r] = 0.f; }
            #pragma unroll
            for (int h = 0; h < 2; ++h) {
                bf16x8 af[4];
                #pragma unroll
                for (int s2 = 0; s2 < 4; ++s2)
                    af[s2] = *(const bf16x8*)((const char*)Kt +
                        swzo(ksub + lr, (h * 64 + s2 * 16 + lg * 8) * 2));
                #pragma unroll
                for (int s2 = 0; s2 < 4; ++s2) {
                    if (do0) s0 = MFMA32(af[s2], qf[0][h * 4 + s2], s0);
                    s1 = MFMA32(af[s2], qf[1][h * 4 + s2], s1);
                }
            }
            if (kmin + 31 > qw) {
                #pragma unroll
                for (int r = 0; r < 16; ++r) {
                    int kg = kmin + (r & 3) + ((r >> 2) << 3) + (lg << 2);
                    s0[r] = (kg > qw + lr)      ? 0.f : s0[r];
                    s1[r] = (kg > qw + 32 + lr) ? 0.f : s1[r];
                }
            }
            unsigned int w0[8], w1[8];
            cvt_swap(s0, w0);
            cvt_swap(s1, w1);
            u32x4 t00 = {w0[0], w0[1], w0[2], w0[3]};
            u32x4 t01 = {w0[4], w0[5], w0[6], w0[7]};
            u32x4 t10 = {w1[0], w1[1], w1[2], w1[3]};
            u32x4 t11 = {w1[4], w1[5], w1[6], w1[7]};
            bf16x8 p00 = __builtin_bit_cast(bf16x8, t00);
            bf16x8 p01 = __builtin_bit_cast(bf16x8, t01);
            bf16x8 p10 = __builtin_bit_cast(bf16x8, t10);
            bf16x8 p11 = __builtin_bit_cast(bf16x8, t11);
            #pragma unroll
            for (int db = 0; db < 4; ++db) {
                bf16x8 vb0 = *(const bf16x8*)((const char*)Vl +
                    swzo(db * 32 + lr, (ksub + lg * 8) * 2));
                bf16x8 vb1 = *(const bf16x8*)((const char*)Vl +
                    swzo(db * 32 + lr, (ksub + 16 + lg * 8) * 2));
                if (do0) {
                    acc[0][db] = MFMA32(p00, vb0, acc[0][db]);
                    acc[0][db] = MFMA32(p01, vb1, acc[0][db]);
                }
                acc[1][db] = MFMA32(p10, vb0, acc[1][db]);
                acc[1][db] = MFMA32(p11, vb1, acc[1][db]);
            }
        }
        __syncthreads();
    }
    float* Ob = Out + (size_t)b * S_LEN * DIM;
    #pragma unroll
    for (int qb = 0; qb < 2; ++qb)
        #pragma unroll
        for (int db = 0; db < 4; ++db)
            #pragma unroll
            for (int r = 0; r < 16; ++r) {
                int q = qw + qb * 32 + (r & 3) + ((r >> 2) << 3) + (lg << 2);
                int d = db * 32 + lr;
                float v = acc[qb][db][r];
                float* p = Ob + (size_t)q * DIM + d;
                if (single) *p = v; else atomicAdd(p, v);
            }
}

extern "C" void kernel_launch(void* const* d_in, const int* in_sizes, int n_in,
                              void* d_out, int out_size, void* d_ws, size_t ws_size,
                              hipStream_t stream) {
    const float* Q = (const float*)d_in[0];
    const float* K = (const float*)d_in[1];
    const float* V = (const float*)d_in[2];
    float* Out = (float*)d_out;

    size_t plane  = (size_t)NB * S_LEN * DIM * sizeof(bf16_t);         // 4 MB
    size_t ghalf  = (size_t)NB * NHC * DIM * DIM * sizeof(bf16_t);     // 8 MB
    size_t gpre   = (size_t)NB * NCH * DIM * DIM * sizeof(bf16_t);     // 4 MB
    char* wsb = (char*)d_ws;
    bf16_t* Qr = (bf16_t*)wsb;
    bf16_t* Kr = (bf16_t*)(wsb + plane);
    bf16_t* Vt = (bf16_t*)(wsb + 2 * plane);

    if (ws_size >= 3 * plane + ghalf + gpre) {
        bf16_t* Gh = (bf16_t*)(wsb + 3 * plane);
        bf16_t* Gp = (bf16_t*)(wsb + 3 * plane + ghalf);
        void* kargs[] = {(void*)&Q, (void*)&K, (void*)&V, (void*)&Qr, (void*)&Kr,
                         (void*)&Vt, (void*)&Gh, (void*)&Gp, (void*)&Out};
        hipLaunchCooperativeKernel((const void*)fused_all_kernel,
                                   dim3(NB * NHC), dim3(256), kargs, 0, stream);
    } else if (ws_size >= 3 * plane) {
        hipMemsetAsync(d_out, 0, (size_t)NB * S_LEN * DIM * sizeof(float), stream);
        prep_fb_kernel<<<ROPE_BLKS + TR_BLKS, 256, 0, stream>>>(Q, K, V, Qr, Kr, Vt);
        int chunks = 0;
        for (int i = 0; i < NQT; ++i) chunks += (2 * (i + 1) + CH_FB - 1) / CH_FB;
        attn_fb_kernel<<<NB * chunks, 256, 0, stream>>>(Qr, Kr, Vt, Out);
    }
}

// Round 14
// 31.959 us; speedup vs baseline: 3.2669x; 3.2669x over previous
//
#include <hip/hip_runtime.h>
#include <hip/hip_bf16.h>

#define S_LEN 4096
#define DIM   128
#define NB    4
#define L_CHUNK 128
#define NCH   (S_LEN / L_CHUNK)      // 32 chunks per batch
#define NHC   (2 * NCH)              // 64 half-chunks per batch
#define ROPE_BLKS (NB * S_LEN / 4)   // fallback prep blocks
#define TR_BLKS   (NB * S_LEN / 64)
#define NQT   (S_LEN / 256)          // fallback: 16 q-tiles per batch
#define CH_FB 3                      // fallback split-K

typedef __bf16 bf16_t;
typedef __attribute__((ext_vector_type(4)))  float        f32x4;
typedef __attribute__((ext_vector_type(8)))  __bf16       bf16x8;
typedef __attribute__((ext_vector_type(16))) float        f32x16;
typedef __attribute__((ext_vector_type(4)))  unsigned int u32x4;

#define MFMA32(a, b, c) __builtin_amdgcn_mfma_f32_32x32x16_bf16((a), (b), (c), 0, 0, 0)
#define CVTPK(d, a, b) asm("v_cvt_pk_bf16_f32 %0, %1, %2" : "=v"(d) : "v"(a), "v"(b))
// vdst HIGH lanes <-> vsrc LOW lanes (verified round 2)
#define PSWAP(d, s)    asm("v_permlane32_swap_b32 %0, %1" : "+v"(d), "+v"(s))

__device__ __forceinline__ unsigned swzo(int row, int colByte) {
    // 256B rows
    return (unsigned)(row * 256 + (colByte ^ ((row & 15) << 4)));
}
__device__ __forceinline__ unsigned swz64(int row, int colByte) {
    // 128B rows (64 bf16 per row)
    return (unsigned)(row * 128 + (colByte ^ ((row & 7) << 4)));
}

__device__ __forceinline__ void cvt_swap(const f32x16& s, unsigned int w[8]) {
    CVTPK(w[0], s[0],  s[1]);  CVTPK(w[1], s[2],  s[3]);
    CVTPK(w[2], s[4],  s[5]);  CVTPK(w[3], s[6],  s[7]);
    CVTPK(w[4], s[8],  s[9]);  CVTPK(w[5], s[10], s[11]);
    CVTPK(w[6], s[12], s[13]); CVTPK(w[7], s[14], s[15]);
    PSWAP(w[0], w[2]); PSWAP(w[1], w[3]);
    PSWAP(w[4], w[6]); PSWAP(w[5], w[7]);
}

__device__ __forceinline__ void ropesc(int seq, int i, float& cc, float& ss) {
    float ex      = -(float)i * (13.287712379549449f / 64.0f);
    float inv_rev = exp2f(ex) * 0.15915494309189535f;
    float rev = (float)seq * inv_rev;
    float fr  = rev - floorf(rev);
    cc = __builtin_amdgcn_cosf(fr);
    ss = __builtin_amdgcn_sinf(fr);
}

// ---------------- K1: rope-K + transpose-stage + G_half + Vt (no Q, no Qr/Kr) ----------------
__launch_bounds__(256, 2)
__global__ void g_kernel(const float* __restrict__ K,
                         const float* __restrict__ V,
                         bf16_t* __restrict__ Vt,
                         bf16_t* __restrict__ Gh) {
    __shared__ bf16_t KsT[128 * 64];  // 16 KB [dk][k_loc] swz64
    __shared__ bf16_t VsT[128 * 64];  // 16 KB [dv][k_loc] swz64
    int b  = blockIdx.x >> 6;
    int hc = blockIdx.x & 63;
    int k0 = hc * 64;
    int tid = threadIdx.x, w = tid >> 6, lane = tid & 63;
    int lr = lane & 31, lg = lane >> 5;

    {
        int srow = tid >> 2;                 // 0..63 local row
        int j    = tid & 3;                  // col quarter
        int s    = k0 + srow;
        size_t base = ((size_t)b * S_LEN + s) * DIM;
        f32x4 kl[4], kh[4], vl[4], vh[4];
        #pragma unroll
        for (int u = 0; u < 4; ++u) {
            kl[u] = *(const f32x4*)(K + base + 16 * j + 4 * u);
            kh[u] = *(const f32x4*)(K + base + 64 + 16 * j + 4 * u);
            vl[u] = *(const f32x4*)(V + base + 16 * j + 4 * u);
            vh[u] = *(const f32x4*)(V + base + 64 + 16 * j + 4 * u);
        }
        #pragma unroll
        for (int e = 0; e < 16; ++e) {
            int i = 16 * j + e;
            float cc, ssn;
            ropesc(s, i, cc, ssn);
            float k1 = kl[e >> 2][e & 3], k2 = kh[e >> 2][e & 3];
            bf16_t okl = (bf16_t)(k1 * cc - k2 * ssn);
            bf16_t okh = (bf16_t)(k2 * cc + k1 * ssn);
            int dk = i;
            *(bf16_t*)((char*)KsT + swz64(dk,      srow * 2)) = okl;
            *(bf16_t*)((char*)KsT + swz64(dk + 64, srow * 2)) = okh;
            *(bf16_t*)((char*)VsT + swz64(dk,      srow * 2)) = (bf16_t)vl[e >> 2][e & 3];
            *(bf16_t*)((char*)VsT + swz64(dk + 64, srow * 2)) = (bf16_t)vh[e >> 2][e & 3];
        }
    }
    __syncthreads();

    f32x16 acc[4];
    #pragma unroll
    for (int db = 0; db < 4; ++db)
        #pragma unroll
        for (int r = 0; r < 16; ++r) acc[db][r] = 0.f;

    #pragma unroll
    for (int sI = 0; sI < 4; ++sI) {
        bf16x8 af = *(const bf16x8*)((const char*)VsT +
            swz64(32 * w + lr, (sI * 16 + lg * 8) * 2));
        #pragma unroll
        for (int db = 0; db < 4; ++db) {
            bf16x8 bfr = *(const bf16x8*)((const char*)KsT +
                swz64(32 * db + lr, (sI * 16 + lg * 8) * 2));
            acc[db] = MFMA32(af, bfr, acc[db]);
        }
    }
    bf16_t* Gc = Gh + ((size_t)b * NHC + hc) * DIM * DIM;
    #pragma unroll
    for (int db = 0; db < 4; ++db)
        #pragma unroll
        for (int r = 0; r < 16; ++r) {
            int dv = 32 * w + (r & 3) + ((r >> 2) << 3) + (lg << 2);
            Gc[(size_t)dv * DIM + 32 * db + lr] = (bf16_t)acc[db][r];
        }

    #pragma unroll
    for (int m = 0; m < 4; ++m) {
        int idx  = tid + 256 * m;            // 0..1023
        int dv   = idx >> 3;
        int slot = idx & 7;
        bf16x8 v = *(const bf16x8*)((const char*)VsT + swz64(dv, slot * 16));
        *(bf16x8*)(Vt + ((size_t)b * DIM + dv) * S_LEN + k0 + slot * 8) = v;
    }
}

// ---------------- K2: exclusive prefix over 64 halves -> Gp per chunk ----------------
__global__ void stage2_kernel(const bf16_t* __restrict__ Gh, bf16_t* __restrict__ Gp) {
    int b = blockIdx.x >> 6;
    int p = (blockIdx.x & 63) * 128 + threadIdx.x;   // pair index [0,8192)
    const bf16_t* ph = Gh + (size_t)b * NHC * DIM * DIM + (size_t)p * 2;
    bf16_t* pp = Gp + (size_t)b * NCH * DIM * DIM + (size_t)p * 2;
    float rlo = 0.f, rhi = 0.f;
    #pragma unroll
    for (int c = 0; c < NCH; ++c) {
        unsigned s = (unsigned)__builtin_bit_cast(unsigned short, (bf16_t)rlo) |
                     ((unsigned)__builtin_bit_cast(unsigned short, (bf16_t)rhi) << 16);
        *(unsigned*)(pp + (size_t)c * DIM * DIM) = s;
        unsigned u0 = *(const unsigned*)(ph + (size_t)(2 * c) * DIM * DIM);
        unsigned u1 = *(const unsigned*)(ph + (size_t)(2 * c + 1) * DIM * DIM);
        rlo += __builtin_bit_cast(float, u0 << 16) + __builtin_bit_cast(float, u1 << 16);
        rhi += __builtin_bit_cast(float, u0 & 0xffff0000u) +
               __builtin_bit_cast(float, u1 & 0xffff0000u);
    }
}

// ---------------- K3: O = Q*Gp + tril(Q Kc^T) Vc  (in-kernel rope, Gs staged, lb(256,1)) ----------------
__launch_bounds__(256, 1)
__global__ void stage3_kernel(const float* __restrict__ Qf,
                              const float* __restrict__ Kf,
                              const bf16_t* __restrict__ Vt,
                              const bf16_t* __restrict__ Gp,
                              float* __restrict__ Out) {
    __shared__ bf16_t Ks[128 * 128];  // 32 KB [k][d] swzo
    __shared__ bf16_t Vs[64 * 128];   // 16 KB [dv-local][k] swzo
    __shared__ bf16_t Gs[64 * 128];   // 16 KB [dv-local][dk] swzo
    int b  = blockIdx.x >> 6;
    int c  = (blockIdx.x >> 1) & 31;
    int dh = blockIdx.x & 1;
    int tid = threadIdx.x, w = tid >> 6, lane = tid & 63;
    int lr = lane & 31, lg = lane >> 5;
    int q0 = c * L_CHUNK;
    const bf16_t* Vb = Vt + (size_t)b * DIM * S_LEN;
    const bf16_t* Gb = Gp + ((size_t)b * NCH + c) * DIM * DIM;

    // Q fragments: rope in-register from fp32 (bit-equivalent to old Qr path)
    bf16x8 qf[8];
    {
        int rowg = q0 + 32 * w + lr;
        const float* Qrow = Qf + ((size_t)b * S_LEN + rowg) * DIM;
        #pragma unroll
        for (int s2 = 0; s2 < 8; ++s2) {
            int c0 = s2 * 16 + lg * 8;
            f32x4 qa0 = *(const f32x4*)(Qrow + c0);
            f32x4 qa1 = *(const f32x4*)(Qrow + c0 + 4);
            f32x4 qb0 = *(const f32x4*)(Qrow + (c0 ^ 64));
            f32x4 qb1 = *(const f32x4*)(Qrow + (c0 ^ 64) + 4);
            float sgn = (c0 < 64) ? -1.f : 1.f;
            bf16x8 o;
            #pragma unroll
            for (int e = 0; e < 8; ++e) {
                float cc, ssn;
                ropesc(rowg, (c0 & 63) + e, cc, ssn);
                float qa = (e < 4) ? qa0[e & 3] : qa1[e & 3];
                float qb = (e < 4) ? qb0[e & 3] : qb1[e & 3];
                o[e] = (bf16_t)(qa * cc + sgn * (qb * ssn));
            }
            qf[s2] = o;
        }
    }

    // K staging with in-flight rope: thread = (row, col-half); same swzo bytes as before
    {
        int row = tid >> 1, sub = tid & 1;
        int rg  = q0 + row;
        const float* Krow = Kf + ((size_t)b * S_LEN + rg) * DIM;
        f32x4 klo[8], khi[8];
        #pragma unroll
        for (int u = 0; u < 8; ++u) {
            klo[u] = *(const f32x4*)(Krow + 32 * sub + 4 * u);
            khi[u] = *(const f32x4*)(Krow + 64 + 32 * sub + 4 * u);
        }
        #pragma unroll
        for (int g = 0; g < 4; ++g) {
            bf16x8 olo, ohi;
            #pragma unroll
            for (int e = 0; e < 8; ++e) {
                int t = 8 * g + e;
                float cc, ssn;
                ropesc(rg, 32 * sub + t, cc, ssn);
                float k1 = klo[t >> 2][t & 3], k2 = khi[t >> 2][t & 3];
                olo[e] = (bf16_t)(k1 * cc - k2 * ssn);
                ohi[e] = (bf16_t)(k2 * cc + k1 * ssn);
            }
            *(bf16x8*)((char*)Ks + swzo(row, (4 * sub + g) * 16)) = olo;
            *(bf16x8*)((char*)Ks + swzo(row, (8 + 4 * sub + g) * 16)) = ohi;
        }
    }

    // Vs staging (bf16 Vt, verified) + Gs staging (r7-verified pattern, halved)
    #pragma unroll
    for (int j = 0; j < 4; ++j) {
        int idx = tid + j * 256;            // row in [0,64)
        int row = idx >> 4, slot = idx & 15;
        u32x4 vd = *(const u32x4*)(Vb + (size_t)(64 * dh + row) * S_LEN + q0 + slot * 8);
        *(u32x4*)((char*)Vs + swzo(row, slot * 16)) = vd;
    }
    if (c > 0) {
        #pragma unroll
        for (int j = 0; j < 4; ++j) {
            int idx = tid + j * 256;
            int row = idx >> 4, slot = idx & 15;
            u32x4 gd = *(const u32x4*)(Gb + (size_t)(64 * dh + row) * DIM + slot * 8);
            *(u32x4*)((char*)Gs + swzo(row, slot * 16)) = gd;
        }
    }
    __syncthreads();

    f32x16 acc[2];
    #pragma unroll
    for (int i = 0; i < 2; ++i)
        #pragma unroll
        for (int r = 0; r < 16; ++r) acc[i][r] = 0.f;

    // part A: O += Q . G_pre (Gs staged)
    if (c > 0) {
        #pragma unroll
        for (int s2 = 0; s2 < 8; ++s2) {
            #pragma unroll
            for (int i = 0; i < 2; ++i) {
                bf16x8 gfr = *(const bf16x8*)((const char*)Gs +
                    swzo(32 * i + lr, (s2 * 16 + lg * 8) * 2));
                acc[i] = MFMA32(qf[s2], gfr, acc[i]);
            }
        }
    }

    // intra: causal within the diagonal chunk (swapped QK^T, cvt_pk+permlane P)
    for (int g = 0; g <= w; ++g) {
        int ksub = g * 32;
        f32x16 sa;
        #pragma unroll
        for (int r = 0; r < 16; ++r) sa[r] = 0.f;
        #pragma unroll
        for (int s2 = 0; s2 < 8; ++s2) {
            bf16x8 af = *(const bf16x8*)((const char*)Ks +
                swzo(ksub + lr, (s2 * 16 + lg * 8) * 2));
            sa = MFMA32(af, qf[s2], sa);
        }
        if (g == w) {
            #pragma unroll
            for (int r = 0; r < 16; ++r) {
                int crow = (r & 3) + ((r >> 2) << 3) + (lg << 2);
                sa[r] = (crow > lr) ? 0.f : sa[r];
            }
        }
        unsigned int wv[8];
        cvt_swap(sa, wv);
        u32x4 tA = {wv[0], wv[1], wv[2], wv[3]};
        u32x4 tB = {wv[4], wv[5], wv[6], wv[7]};
        bf16x8 pA = __builtin_bit_cast(bf16x8, tA);
        bf16x8 pB = __builtin_bit_cast(bf16x8, tB);
        #pragma unroll
        for (int i = 0; i < 2; ++i) {
            bf16x8 v0 = *(const bf16x8*)((const char*)Vs +
                swzo(32 * i + lr, (ksub + lg * 8) * 2));
            bf16x8 v1 = *(const bf16x8*)((const char*)Vs +
                swzo(32 * i + lr, (ksub + 16 + lg * 8) * 2));
            acc[i] = MFMA32(pA, v0, acc[i]);
            acc[i] = MFMA32(pB, v1, acc[i]);
        }
    }

    float* Ob = Out + (size_t)b * S_LEN * DIM;
    #pragma unroll
    for (int i = 0; i < 2; ++i)
        #pragma unroll
        for (int r = 0; r < 16; ++r) {
            int q = q0 + 32 * w + (r & 3) + ((r >> 2) << 3) + (lg << 2);
            int d = 64 * dh + 32 * i + lr;
            Ob[(size_t)q * DIM + d] = acc[i][r];
        }
}

// ---------------- fallback path (small ws): r2-verified prep + atomic kernel ----------------
__global__ void prep_fb_kernel(const float* __restrict__ Q,
                               const float* __restrict__ K,
                               const float* __restrict__ V,
                               bf16_t* __restrict__ Qr,
                               bf16_t* __restrict__ Kr,
                               bf16_t* __restrict__ Vt) {
    int bid = blockIdx.x;
    int t   = threadIdx.x;
    if (bid < ROPE_BLKS) {
        int i   = t & 63;
        int row = bid * 4 + (t >> 6);
        int s   = row & (S_LEN - 1);
        size_t base = (size_t)row * DIM;
        float cc, ssn;
        ropesc(s, i, cc, ssn);
        float q1 = Q[base + i], q2 = Q[base + i + 64];
        float k1 = K[base + i], k2 = K[base + i + 64];
        Qr[base + i]      = (bf16_t)(q1 * cc - q2 * ssn);
        Qr[base + i + 64] = (bf16_t)(q2 * cc + q1 * ssn);
        Kr[base + i]      = (bf16_t)(k1 * cc - k2 * ssn);
        Kr[base + i + 64] = (bf16_t)(k2 * cc + k1 * ssn);
    } else {
        int idx = bid - ROPE_BLKS;
        int b   = idx >> 6;
        int s0  = (idx & 63) * 64;
        int d   = t >> 1;
        int sh  = (t & 1) * 32;
        const float* vb = V + (size_t)b * S_LEN * DIM;
        bf16_t* ob = Vt + ((size_t)b * DIM + d) * S_LEN;
        #pragma unroll
        for (int j8 = 0; j8 < 4; ++j8) {
            bf16x8 u;
            #pragma unroll
            for (int e2 = 0; e2 < 8; ++e2) {
                int s = s0 + sh + j8 * 8 + e2;
                u[e2] = (bf16_t)vb[(size_t)s * DIM + d];
            }
            *(bf16x8*)(ob + s0 + sh + j8 * 8) = u;
        }
    }
}

__launch_bounds__(256, 2)
__global__ void attn_fb_kernel(const bf16_t* __restrict__ Qr,
                               const bf16_t* __restrict__ Kr,
                               const bf16_t* __restrict__ Vt,
                               float* __restrict__ Out) {
    __shared__ bf16_t Kt[128 * 128];
    __shared__ bf16_t Vl[128 * 128];
    int b = blockIdx.x & 3;
    int t = blockIdx.x >> 2;
    int qt = 0, c0 = 0;
    for (int i2 = NQT - 1; i2 >= 0; --i2) {
        int n = (2 * (i2 + 1) + CH_FB - 1) / CH_FB;
        if (t < n) { qt = i2; c0 = t; break; }
        t -= n;
    }
    int nkt   = 2 * (qt + 1);
    int kt_lo = c0 * CH_FB;
    int kt_hi = min(kt_lo + CH_FB, nkt);
    bool single = ((nkt + CH_FB - 1) / CH_FB) == 1;

    int tid = threadIdx.x, w = tid >> 6, lane = tid & 63;
    int lr = lane & 31, lg = lane >> 5;
    int qw = qt * 256 + w * 64;
    const bf16_t* Qb = Qr + (size_t)b * S_LEN * DIM;
    const bf16_t* Kb = Kr + (size_t)b * S_LEN * DIM;
    const bf16_t* Vb = Vt + (size_t)b * DIM * S_LEN;

    bf16x8 qf[2][8];
    #pragma unroll
    for (int qb = 0; qb < 2; ++qb)
        #pragma unroll
        for (int s2 = 0; s2 < 8; ++s2)
            qf[qb][s2] = *(const bf16x8*)(Qb + (size_t)(qw + qb * 32 + lr) * DIM
                                          + s2 * 16 + lg * 8);
    f32x16 acc[2][4];
    #pragma unroll
    for (int qb = 0; qb < 2; ++qb)
        #pragma unroll
        for (int db = 0; db < 4; ++db)
            #pragma unroll
            for (int r = 0; r < 16; ++r) acc[qb][db][r] = 0.f;

    for (int kt = kt_lo; kt < kt_hi; ++kt) {
        int kbase = kt * 128;
        #pragma unroll
        for (int j = 0; j < 8; ++j) {
            int idx = tid + j * 256;
            int row = idx >> 4, slot = idx & 15;
            u32x4 kd = *(const u32x4*)(Kb + (size_t)(kbase + row) * DIM + slot * 8);
            *(u32x4*)((char*)Kt + swzo(row, slot * 16)) = kd;
            u32x4 vd = *(const u32x4*)(Vb + (size_t)row * S_LEN + kbase + slot * 8);
            *(u32x4*)((char*)Vl + swzo(row, slot * 16)) = vd;
        }
        __syncthreads();
        #pragma unroll
        for (int kb = 0; kb < 4; ++kb) {
            int ksub = kb * 32;
            int kmin = kbase + ksub;
            if (kmin > qw + 63) break;
            bool do0 = (kmin <= qw + 31);
            f32x16 s0, s1;
            #pragma unroll
            for (int r = 0; r < 16; ++r) { s0[r] = 0.f; s1[r] = 0.f; }
            #pragma unroll
            for (int h = 0; h < 2; ++h) {
                bf16x8 af[4];
                #pragma unroll
                for (int s2 = 0; s2 < 4; ++s2)
                    af[s2] = *(const bf16x8*)((const char*)Kt +
                        swzo(ksub + lr, (h * 64 + s2 * 16 + lg * 8) * 2));
                #pragma unroll
                for (int s2 = 0; s2 < 4; ++s2) {
                    if (do0) s0 = MFMA32(af[s2], qf[0][h * 4 + s2], s0);
                    s1 = MFMA32(af[s2], qf[1][h * 4 + s2], s1);
                }
            }
            if (kmin + 31 > qw) {
                #pragma unroll
                for (int r = 0; r < 16; ++r) {
                    int kg = kmin + (r & 3) + ((r >> 2) << 3) + (lg << 2);
                    s0[r] = (kg > qw + lr)      ? 0.f : s0[r];
                    s1[r] = (kg > qw + 32 + lr) ? 0.f : s1[r];
                }
            }
            unsigned int w0[8], w1[8];
            cvt_swap(s0, w0);
            cvt_swap(s1, w1);
            u32x4 t00 = {w0[0], w0[1], w0[2], w0[3]};
            u32x4 t01 = {w0[4], w0[5], w0[6], w0[7]};
            u32x4 t10 = {w1[0], w1[1], w1[2], w1[3]};
            u32x4 t11 = {w1[4], w1[5], w1[6], w1[7]};
            bf16x8 p00 = __builtin_bit_cast(bf16x8, t00);
            bf16x8 p01 = __builtin_bit_cast(bf16x8, t01);
            bf16x8 p10 = __builtin_bit_cast(bf16x8, t10);
            bf16x8 p11 = __builtin_bit_cast(bf16x8, t11);
            #pragma unroll
            for (int db = 0; db < 4; ++db) {
                bf16x8 vb0 = *(const bf16x8*)((const char*)Vl +
                    swzo(db * 32 + lr, (ksub + lg * 8) * 2));
                bf16x8 vb1 = *(const bf16x8*)((const char*)Vl +
                    swzo(db * 32 + lr, (ksub + 16 + lg * 8) * 2));
                if (do0) {
                    acc[0][db] = MFMA32(p00, vb0, acc[0][db]);
                    acc[0][db] = MFMA32(p01, vb1, acc[0][db]);
                }
                acc[1][db] = MFMA32(p10, vb0, acc[1][db]);
                acc[1][db] = MFMA32(p11, vb1, acc[1][db]);
            }
        }
        __syncthreads();
    }
    float* Ob = Out + (size_t)b * S_LEN * DIM;
    #pragma unroll
    for (int qb = 0; qb < 2; ++qb)
        #pragma unroll
        for (int db = 0; db < 4; ++db)
            #pragma unroll
            for (int r = 0; r < 16; ++r) {
                int q = qw + qb * 32 + (r & 3) + ((r >> 2) << 3) + (lg << 2);
                int d = db * 32 + lr;
                float v = acc[qb][db][r];
                float* p = Ob + (size_t)q * DIM + d;
                if (single) *p = v; else atomicAdd(p, v);
            }
}

extern "C" void kernel_launch(void* const* d_in, const int* in_sizes, int n_in,
                              void* d_out, int out_size, void* d_ws, size_t ws_size,
                              hipStream_t stream) {
    const float* Q = (const float*)d_in[0];
    const float* K = (const float*)d_in[1];
    const float* V = (const float*)d_in[2];
    float* Out = (float*)d_out;

    size_t plane  = (size_t)NB * S_LEN * DIM * sizeof(bf16_t);         // 4 MB
    size_t ghalf  = (size_t)NB * NHC * DIM * DIM * sizeof(bf16_t);     // 8 MB
    size_t gpre   = (size_t)NB * NCH * DIM * DIM * sizeof(bf16_t);     // 4 MB
    char* wsb = (char*)d_ws;

    if (ws_size >= plane + ghalf + gpre) {
        bf16_t* Vt = (bf16_t*)wsb;
        bf16_t* Gh = (bf16_t*)(wsb + plane);
        bf16_t* Gp = (bf16_t*)(wsb + plane + ghalf);
        g_kernel<<<NB * NHC, 256, 0, stream>>>(K, V, Vt, Gh);
        stage2_kernel<<<NB * 64, 128, 0, stream>>>(Gh, Gp);
        stage3_kernel<<<NB * NCH * 2, 256, 0, stream>>>(Q, K, Vt, Gp, Out);
    } else if (ws_size >= 3 * plane) {
        bf16_t* Qr = (bf16_t*)wsb;
        bf16_t* Kr = (bf16_t*)(wsb + plane);
        bf16_t* Vt = (bf16_t*)(wsb + 2 * plane);
        hipMemsetAsync(d_out, 0, (size_t)NB * S_LEN * DIM * sizeof(float), stream);
        prep_fb_kernel<<<ROPE_BLKS + TR_BLKS, 256, 0, stream>>>(Q, K, V, Qr, Kr, Vt);
        int chunks = 0;
        for (int i = 0; i < NQT; ++i) chunks += (2 * (i + 1) + CH_FB - 1) / CH_FB;
        attn_fb_kernel<<<NB * chunks, 256, 0, stream>>>(Qr, Kr, Vt, Out);
    }
}

// Round 15
// 31.095 us; speedup vs baseline: 3.3576x; 1.0278x over previous
//
#include <hip/hip_runtime.h>
#include <hip/hip_bf16.h>

#define S_LEN 4096
#define DIM   128
#define NB    4
#define L_CHUNK 128
#define NCH   (S_LEN / L_CHUNK)      // 32 chunks per batch
#define NHC   (2 * NCH)              // 64 half-chunks per batch
#define ROPE_BLKS (NB * S_LEN / 4)   // fallback prep blocks
#define TR_BLKS   (NB * S_LEN / 64)
#define NQT   (S_LEN / 256)          // fallback: 16 q-tiles per batch
#define CH_FB 3                      // fallback split-K

typedef __bf16 bf16_t;
typedef __attribute__((ext_vector_type(4)))  float        f32x4;
typedef __attribute__((ext_vector_type(8)))  __bf16       bf16x8;
typedef __attribute__((ext_vector_type(16))) float        f32x16;
typedef __attribute__((ext_vector_type(4)))  unsigned int u32x4;

#define MFMA32(a, b, c) __builtin_amdgcn_mfma_f32_32x32x16_bf16((a), (b), (c), 0, 0, 0)
#define CVTPK(d, a, b) asm("v_cvt_pk_bf16_f32 %0, %1, %2" : "=v"(d) : "v"(a), "v"(b))
// vdst HIGH lanes <-> vsrc LOW lanes (verified round 2)
#define PSWAP(d, s)    asm("v_permlane32_swap_b32 %0, %1" : "+v"(d), "+v"(s))

__device__ __forceinline__ unsigned swzo(int row, int colByte) {
    // 256B rows
    return (unsigned)(row * 256 + (colByte ^ ((row & 15) << 4)));
}
__device__ __forceinline__ unsigned swz64(int row, int colByte) {
    // 128B rows (64 bf16 per row)
    return (unsigned)(row * 128 + (colByte ^ ((row & 7) << 4)));
}

__device__ __forceinline__ void cvt_swap(const f32x16& s, unsigned int w[8]) {
    CVTPK(w[0], s[0],  s[1]);  CVTPK(w[1], s[2],  s[3]);
    CVTPK(w[2], s[4],  s[5]);  CVTPK(w[3], s[6],  s[7]);
    CVTPK(w[4], s[8],  s[9]);  CVTPK(w[5], s[10], s[11]);
    CVTPK(w[6], s[12], s[13]); CVTPK(w[7], s[14], s[15]);
    PSWAP(w[0], w[2]); PSWAP(w[1], w[3]);
    PSWAP(w[4], w[6]); PSWAP(w[5], w[7]);
}

__device__ __forceinline__ void ropesc(int seq, int i, float& cc, float& ss) {
    float ex      = -(float)i * (13.287712379549449f / 64.0f);
    float inv_rev = exp2f(ex) * 0.15915494309189535f;
    float rev = (float)seq * inv_rev;
    float fr  = rev - floorf(rev);
    cc = __builtin_amdgcn_cosf(fr);
    ss = __builtin_amdgcn_sinf(fr);
}

// ---------------- K1: rope-K -> Kr + transpose-stage + G_half + Vt (no Q) ----------------
__launch_bounds__(256, 2)
__global__ void g_kernel(const float* __restrict__ K,
                         const float* __restrict__ V,
                         bf16_t* __restrict__ Kr,
                         bf16_t* __restrict__ Vt,
                         bf16_t* __restrict__ Gh) {
    __shared__ bf16_t KsT[128 * 64];  // 16 KB [dk][k_loc] swz64
    __shared__ bf16_t VsT[128 * 64];  // 16 KB [dv][k_loc] swz64
    int b  = blockIdx.x >> 6;
    int hc = blockIdx.x & 63;
    int k0 = hc * 64;
    int tid = threadIdx.x, w = tid >> 6, lane = tid & 63;
    int lr = lane & 31, lg = lane >> 5;

    {
        int srow = tid >> 2;                 // 0..63 local row
        int j    = tid & 3;                  // col quarter
        int s    = k0 + srow;
        size_t base = ((size_t)b * S_LEN + s) * DIM;
        f32x4 kl[4], kh[4], vl[4], vh[4];
        #pragma unroll
        for (int u = 0; u < 4; ++u) {
            kl[u] = *(const f32x4*)(K + base + 16 * j + 4 * u);
            kh[u] = *(const f32x4*)(K + base + 64 + 16 * j + 4 * u);
            vl[u] = *(const f32x4*)(V + base + 16 * j + 4 * u);
            vh[u] = *(const f32x4*)(V + base + 64 + 16 * j + 4 * u);
        }
        bf16_t okl[16], okh[16];
        #pragma unroll
        for (int e = 0; e < 16; ++e) {
            int i = 16 * j + e;
            float cc, ssn;
            ropesc(s, i, cc, ssn);
            float k1 = kl[e >> 2][e & 3], k2 = kh[e >> 2][e & 3];
            okl[e] = (bf16_t)(k1 * cc - k2 * ssn);
            okh[e] = (bf16_t)(k2 * cc + k1 * ssn);
            *(bf16_t*)((char*)KsT + swz64(i,      srow * 2)) = okl[e];
            *(bf16_t*)((char*)KsT + swz64(i + 64, srow * 2)) = okh[e];
            *(bf16_t*)((char*)VsT + swz64(i,      srow * 2)) = (bf16_t)vl[e >> 2][e & 3];
            *(bf16_t*)((char*)VsT + swz64(i + 64, srow * 2)) = (bf16_t)vh[e >> 2][e & 3];
        }
        // Kr global (coalesced 16B), needed by stage3's K staging
        #pragma unroll
        for (int hlf = 0; hlf < 2; ++hlf) {
            *(bf16x8*)(Kr + base + 16 * j + 8 * hlf)      = *(bf16x8*)&okl[8 * hlf];
            *(bf16x8*)(Kr + base + 64 + 16 * j + 8 * hlf) = *(bf16x8*)&okh[8 * hlf];
        }
    }
    __syncthreads();

    f32x16 acc[4];
    #pragma unroll
    for (int db = 0; db < 4; ++db)
        #pragma unroll
        for (int r = 0; r < 16; ++r) acc[db][r] = 0.f;

    #pragma unroll
    for (int sI = 0; sI < 4; ++sI) {
        bf16x8 af = *(const bf16x8*)((const char*)VsT +
            swz64(32 * w + lr, (sI * 16 + lg * 8) * 2));
        #pragma unroll
        for (int db = 0; db < 4; ++db) {
            bf16x8 bfr = *(const bf16x8*)((const char*)KsT +
                swz64(32 * db + lr, (sI * 16 + lg * 8) * 2));
            acc[db] = MFMA32(af, bfr, acc[db]);
        }
    }
    bf16_t* Gc = Gh + ((size_t)b * NHC + hc) * DIM * DIM;
    #pragma unroll
    for (int db = 0; db < 4; ++db)
        #pragma unroll
        for (int r = 0; r < 16; ++r) {
            int dv = 32 * w + (r & 3) + ((r >> 2) << 3) + (lg << 2);
            Gc[(size_t)dv * DIM + 32 * db + lr] = (bf16_t)acc[db][r];
        }

    #pragma unroll
    for (int m = 0; m < 4; ++m) {
        int idx  = tid + 256 * m;            // 0..1023
        int dv   = idx >> 3;
        int slot = idx & 7;
        bf16x8 v = *(const bf16x8*)((const char*)VsT + swz64(dv, slot * 16));
        *(bf16x8*)(Vt + ((size_t)b * DIM + dv) * S_LEN + k0 + slot * 8) = v;
    }
}

// ---------------- K2: exclusive prefix over 64 halves -> Gp per chunk ----------------
__global__ void stage2_kernel(const bf16_t* __restrict__ Gh, bf16_t* __restrict__ Gp) {
    int b = blockIdx.x >> 6;
    int p = (blockIdx.x & 63) * 128 + threadIdx.x;   // pair index [0,8192)
    const bf16_t* ph = Gh + (size_t)b * NHC * DIM * DIM + (size_t)p * 2;
    bf16_t* pp = Gp + (size_t)b * NCH * DIM * DIM + (size_t)p * 2;
    float rlo = 0.f, rhi = 0.f;
    #pragma unroll
    for (int c = 0; c < NCH; ++c) {
        unsigned s = (unsigned)__builtin_bit_cast(unsigned short, (bf16_t)rlo) |
                     ((unsigned)__builtin_bit_cast(unsigned short, (bf16_t)rhi) << 16);
        *(unsigned*)(pp + (size_t)c * DIM * DIM) = s;
        unsigned u0 = *(const unsigned*)(ph + (size_t)(2 * c) * DIM * DIM);
        unsigned u1 = *(const unsigned*)(ph + (size_t)(2 * c + 1) * DIM * DIM);
        rlo += __builtin_bit_cast(float, u0 << 16) + __builtin_bit_cast(float, u1 << 16);
        rhi += __builtin_bit_cast(float, u0 & 0xffff0000u) +
               __builtin_bit_cast(float, u1 & 0xffff0000u);
    }
}

// ---------------- K3: O = Q*Gp + tril(Q Kc^T) Vc  (Q-rope in-reg; Kr staged; lb(256,1)) ----------------
__launch_bounds__(256, 1)
__global__ void stage3_kernel(const float* __restrict__ Qf,
                              const bf16_t* __restrict__ Kr,
                              const bf16_t* __restrict__ Vt,
                              const bf16_t* __restrict__ Gp,
                              float* __restrict__ Out) {
    __shared__ bf16_t Ks[128 * 128];  // 32 KB [k][d] swzo
    __shared__ bf16_t Vs[64 * 128];   // 16 KB [dv-local][k] swzo
    int b  = blockIdx.x >> 6;
    int c  = (blockIdx.x >> 1) & 31;
    int dh = blockIdx.x & 1;
    int tid = threadIdx.x, w = tid >> 6, lane = tid & 63;
    int lr = lane & 31, lg = lane >> 5;
    int q0 = c * L_CHUNK;
    const bf16_t* Kb = Kr + (size_t)b * S_LEN * DIM;
    const bf16_t* Vb = Vt + (size_t)b * DIM * S_LEN;
    const bf16_t* Gb = Gp + ((size_t)b * NCH + c) * DIM * DIM;

    // Q fragments: rope in-register from fp32 (r14-verified)
    bf16x8 qf[8];
    {
        int rowg = q0 + 32 * w + lr;
        const float* Qrow = Qf + ((size_t)b * S_LEN + rowg) * DIM;
        #pragma unroll
        for (int s2 = 0; s2 < 8; ++s2) {
            int c0 = s2 * 16 + lg * 8;
            f32x4 qa0 = *(const f32x4*)(Qrow + c0);
            f32x4 qa1 = *(const f32x4*)(Qrow + c0 + 4);
            f32x4 qb0 = *(const f32x4*)(Qrow + (c0 ^ 64));
            f32x4 qb1 = *(const f32x4*)(Qrow + (c0 ^ 64) + 4);
            float sgn = (c0 < 64) ? -1.f : 1.f;
            bf16x8 o;
            #pragma unroll
            for (int e = 0; e < 8; ++e) {
                float cc, ssn;
                ropesc(rowg, (c0 & 63) + e, cc, ssn);
                float qa = (e < 4) ? qa0[e & 3] : qa1[e & 3];
                float qb = (e < 4) ? qb0[e & 3] : qb1[e & 3];
                o[e] = (bf16_t)(qa * cc + sgn * (qb * ssn));
            }
            qf[s2] = o;
        }
    }

    // K staging from bf16 Kr (r12-verified fast path)
    #pragma unroll
    for (int j = 0; j < 8; ++j) {
        int idx = tid + j * 256;
        int row = idx >> 4, slot = idx & 15;
        u32x4 kd = *(const u32x4*)(Kb + (size_t)(q0 + row) * DIM + slot * 8);
        *(u32x4*)((char*)Ks + swzo(row, slot * 16)) = kd;
    }
    #pragma unroll
    for (int j = 0; j < 4; ++j) {
        int idx = tid + j * 256;            // row in [0,64)
        int row = idx >> 4, slot = idx & 15;
        u32x4 vd = *(const u32x4*)(Vb + (size_t)(64 * dh + row) * S_LEN + q0 + slot * 8);
        *(u32x4*)((char*)Vs + swzo(row, slot * 16)) = vd;
    }
    __syncthreads();

    f32x16 acc[2];
    #pragma unroll
    for (int i = 0; i < 2; ++i)
        #pragma unroll
        for (int r = 0; r < 16; ++r) acc[i][r] = 0.f;

    // part A: O += Q . G_pre (Gp direct from global, r10-verified)
    if (c > 0) {
        #pragma unroll
        for (int s2 = 0; s2 < 8; ++s2) {
            #pragma unroll
            for (int i = 0; i < 2; ++i) {
                bf16x8 gfr = *(const bf16x8*)(Gb +
                    (size_t)(64 * dh + 32 * i + lr) * DIM + s2 * 16 + lg * 8);
                acc[i] = MFMA32(qf[s2], gfr, acc[i]);
            }
        }
    }

    // intra: causal within the diagonal chunk (swapped QK^T, cvt_pk+permlane P)
    for (int g = 0; g <= w; ++g) {
        int ksub = g * 32;
        f32x16 sa;
        #pragma unroll
        for (int r = 0; r < 16; ++r) sa[r] = 0.f;
        #pragma unroll
        for (int s2 = 0; s2 < 8; ++s2) {
            bf16x8 af = *(const bf16x8*)((const char*)Ks +
                swzo(ksub + lr, (s2 * 16 + lg * 8) * 2));
            sa = MFMA32(af, qf[s2], sa);
        }
        if (g == w) {
            #pragma unroll
            for (int r = 0; r < 16; ++r) {
                int crow = (r & 3) + ((r >> 2) << 3) + (lg << 2);
                sa[r] = (crow > lr) ? 0.f : sa[r];
            }
        }
        unsigned int wv[8];
        cvt_swap(sa, wv);
        u32x4 tA = {wv[0], wv[1], wv[2], wv[3]};
        u32x4 tB = {wv[4], wv[5], wv[6], wv[7]};
        bf16x8 pA = __builtin_bit_cast(bf16x8, tA);
        bf16x8 pB = __builtin_bit_cast(bf16x8, tB);
        #pragma unroll
        for (int i = 0; i < 2; ++i) {
            bf16x8 v0 = *(const bf16x8*)((const char*)Vs +
                swzo(32 * i + lr, (ksub + lg * 8) * 2));
            bf16x8 v1 = *(const bf16x8*)((const char*)Vs +
                swzo(32 * i + lr, (ksub + 16 + lg * 8) * 2));
            acc[i] = MFMA32(pA, v0, acc[i]);
            acc[i] = MFMA32(pB, v1, acc[i]);
        }
    }

    float* Ob = Out + (size_t)b * S_LEN * DIM;
    #pragma unroll
    for (int i = 0; i < 2; ++i)
        #pragma unroll
        for (int r = 0; r < 16; ++r) {
            int q = q0 + 32 * w + (r & 3) + ((r >> 2) << 3) + (lg << 2);
            int d = 64 * dh + 32 * i + lr;
            Ob[(size_t)q * DIM + d] = acc[i][r];
        }
}

// ---------------- fallback path (small ws): r2-verified prep + atomic kernel ----------------
__global__ void prep_fb_kernel(const float* __restrict__ Q,
                               const float* __restrict__ K,
                               const float* __restrict__ V,
                               bf16_t* __restrict__ Qr,
                               bf16_t* __restrict__ Kr,
                               bf16_t* __restrict__ Vt) {
    int bid = blockIdx.x;
    int t   = threadIdx.x;
    if (bid < ROPE_BLKS) {
        int i   = t & 63;
        int row = bid * 4 + (t >> 6);
        int s   = row & (S_LEN - 1);
        size_t base = (size_t)row * DIM;
        float cc, ssn;
        ropesc(s, i, cc, ssn);
        float q1 = Q[base + i], q2 = Q[base + i + 64];
        float k1 = K[base + i], k2 = K[base + i + 64];
        Qr[base + i]      = (bf16_t)(q1 * cc - q2 * ssn);
        Qr[base + i + 64] = (bf16_t)(q2 * cc + q1 * ssn);
        Kr[base + i]      = (bf16_t)(k1 * cc - k2 * ssn);
        Kr[base + i + 64] = (bf16_t)(k2 * cc + k1 * ssn);
    } else {
        int idx = bid - ROPE_BLKS;
        int b   = idx >> 6;
        int s0  = (idx & 63) * 64;
        int d   = t >> 1;
        int sh  = (t & 1) * 32;
        const float* vb = V + (size_t)b * S_LEN * DIM;
        bf16_t* ob = Vt + ((size_t)b * DIM + d) * S_LEN;
        #pragma unroll
        for (int j8 = 0; j8 < 4; ++j8) {
            bf16x8 u;
            #pragma unroll
            for (int e2 = 0; e2 < 8; ++e2) {
                int s = s0 + sh + j8 * 8 + e2;
                u[e2] = (bf16_t)vb[(size_t)s * DIM + d];
            }
            *(bf16x8*)(ob + s0 + sh + j8 * 8) = u;
        }
    }
}

__launch_bounds__(256, 2)
__global__ void attn_fb_kernel(const bf16_t* __restrict__ Qr,
                               const bf16_t* __restrict__ Kr,
                               const bf16_t* __restrict__ Vt,
                               float* __restrict__ Out) {
    __shared__ bf16_t Kt[128 * 128];
    __shared__ bf16_t Vl[128 * 128];
    int b = blockIdx.x & 3;
    int t = blockIdx.x >> 2;
    int qt = 0, c0 = 0;
    for (int i2 = NQT - 1; i2 >= 0; --i2) {
        int n = (2 * (i2 + 1) + CH_FB - 1) / CH_FB;
        if (t < n) { qt = i2; c0 = t; break; }
        t -= n;
    }
    int nkt   = 2 * (qt + 1);
    int kt_lo = c0 * CH_FB;
    int kt_hi = min(kt_lo + CH_FB, nkt);
    bool single = ((nkt + CH_FB - 1) / CH_FB) == 1;

    int tid = threadIdx.x, w = tid >> 6, lane = tid & 63;
    int lr = lane & 31, lg = lane >> 5;
    int qw = qt * 256 + w * 64;
    const bf16_t* Qb = Qr + (size_t)b * S_LEN * DIM;
    const bf16_t* Kb = Kr + (size_t)b * S_LEN * DIM;
    const bf16_t* Vb = Vt + (size_t)b * DIM * S_LEN;

    bf16x8 qf[2][8];
    #pragma unroll
    for (int qb = 0; qb < 2; ++qb)
        #pragma unroll
        for (int s2 = 0; s2 < 8; ++s2)
            qf[qb][s2] = *(const bf16x8*)(Qb + (size_t)(qw + qb * 32 + lr) * DIM
                                          + s2 * 16 + lg * 8);
    f32x16 acc[2][4];
    #pragma unroll
    for (int qb = 0; qb < 2; ++qb)
        #pragma unroll
        for (int db = 0; db < 4; ++db)
            #pragma unroll
            for (int r = 0; r < 16; ++r) acc[qb][db][r] = 0.f;

    for (int kt = kt_lo; kt < kt_hi; ++kt) {
        int kbase = kt * 128;
        #pragma unroll
        for (int j = 0; j < 8; ++j) {
            int idx = tid + j * 256;
            int row = idx >> 4, slot = idx & 15;
            u32x4 kd = *(const u32x4*)(Kb + (size_t)(kbase + row) * DIM + slot * 8);
            *(u32x4*)((char*)Kt + swzo(row, slot * 16)) = kd;
            u32x4 vd = *(const u32x4*)(Vb + (size_t)row * S_LEN + kbase + slot * 8);
            *(u32x4*)((char*)Vl + swzo(row, slot * 16)) = vd;
        }
        __syncthreads();
        #pragma unroll
        for (int kb = 0; kb < 4; ++kb) {
            int ksub = kb * 32;
            int kmin = kbase + ksub;
            if (kmin > qw + 63) break;
            bool do0 = (kmin <= qw + 31);
            f32x16 s0, s1;
            #pragma unroll
            for (int r = 0; r < 16; ++r) { s0[r] = 0.f; s1[r] = 0.f; }
            #pragma unroll
            for (int h = 0; h < 2; ++h) {
                bf16x8 af[4];
                #pragma unroll
                for (int s2 = 0; s2 < 4; ++s2)
                    af[s2] = *(const bf16x8*)((const char*)Kt +
                        swzo(ksub + lr, (h * 64 + s2 * 16 + lg * 8) * 2));
                #pragma unroll
                for (int s2 = 0; s2 < 4; ++s2) {
                    if (do0) s0 = MFMA32(af[s2], qf[0][h * 4 + s2], s0);
                    s1 = MFMA32(af[s2], qf[1][h * 4 + s2], s1);
                }
            }
            if (kmin + 31 > qw) {
                #pragma unroll
                for (int r = 0; r < 16; ++r) {
                    int kg = kmin + (r & 3) + ((r >> 2) << 3) + (lg << 2);
                    s0[r] = (kg > qw + lr)      ? 0.f : s0[r];
                    s1[r] = (kg > qw + 32 + lr) ? 0.f : s1[r];
                }
            }
            unsigned int w0[8], w1[8];
            cvt_swap(s0, w0);
            cvt_swap(s1, w1);
            u32x4 t00 = {w0[0], w0[1], w0[2], w0[3]};
            u32x4 t01 = {w0[4], w0[5], w0[6], w0[7]};
            u32x4 t10 = {w1[0], w1[1], w1[2], w1[3]};
            u32x4 t11 = {w1[4], w1[5], w1[6], w1[7]};
            bf16x8 p00 = __builtin_bit_cast(bf16x8, t00);
            bf16x8 p01 = __builtin_bit_cast(bf16x8, t01);
            bf16x8 p10 = __builtin_bit_cast(bf16x8, t10);
            bf16x8 p11 = __builtin_bit_cast(bf16x8, t11);
            #pragma unroll
            for (int db = 0; db < 4; ++db) {
                bf16x8 vb0 = *(const bf16x8*)((const char*)Vl +
                    swzo(db * 32 + lr, (ksub + lg * 8) * 2));
                bf16x8 vb1 = *(const bf16x8*)((const char*)Vl +
                    swzo(db * 32 + lr, (ksub + 16 + lg * 8) * 2));
                if (do0) {
                    acc[0][db] = MFMA32(p00, vb0, acc[0][db]);
                    acc[0][db] = MFMA32(p01, vb1, acc[0][db]);
                }
                acc[1][db] = MFMA32(p10, vb0, acc[1][db]);
                acc[1][db] = MFMA32(p11, vb1, acc[1][db]);
            }
        }
        __syncthreads();
    }
    float* Ob = Out + (size_t)b * S_LEN * DIM;
    #pragma unroll
    for (int qb = 0; qb < 2; ++qb)
        #pragma unroll
        for (int db = 0; db < 4; ++db)
            #pragma unroll
            for (int r = 0; r < 16; ++r) {
                int q = qw + qb * 32 + (r & 3) + ((r >> 2) << 3) + (lg << 2);
                int d = db * 32 + lr;
                float v = acc[qb][db][r];
                float* p = Ob + (size_t)q * DIM + d;
                if (single) *p = v; else atomicAdd(p, v);
            }
}

extern "C" void kernel_launch(void* const* d_in, const int* in_sizes, int n_in,
                              void* d_out, int out_size, void* d_ws, size_t ws_size,
                              hipStream_t stream) {
    const float* Q = (const float*)d_in[0];
    const float* K = (const float*)d_in[1];
    const float* V = (const float*)d_in[2];
    float* Out = (float*)d_out;

    size_t plane  = (size_t)NB * S_LEN * DIM * sizeof(bf16_t);         // 4 MB
    size_t ghalf  = (size_t)NB * NHC * DIM * DIM * sizeof(bf16_t);     // 8 MB
    size_t gpre   = (size_t)NB * NCH * DIM * DIM * sizeof(bf16_t);     // 4 MB
    char* wsb = (char*)d_ws;

    if (ws_size >= 2 * plane + ghalf + gpre) {
        bf16_t* Kr = (bf16_t*)wsb;
        bf16_t* Vt = (bf16_t*)(wsb + plane);
        bf16_t* Gh = (bf16_t*)(wsb + 2 * plane);
        bf16_t* Gp = (bf16_t*)(wsb + 2 * plane + ghalf);
        g_kernel<<<NB * NHC, 256, 0, stream>>>(K, V, Kr, Vt, Gh);
        stage2_kernel<<<NB * 64, 128, 0, stream>>>(Gh, Gp);
        stage3_kernel<<<NB * NCH * 2, 256, 0, stream>>>(Q, Kr, Vt, Gp, Out);
    } else if (ws_size >= 3 * plane) {
        bf16_t* Qr = (bf16_t*)wsb;
        bf16_t* Kr = (bf16_t*)(wsb + plane);
        bf16_t* Vt = (bf16_t*)(wsb + 2 * plane);
        hipMemsetAsync(d_out, 0, (size_t)NB * S_LEN * DIM * sizeof(float), stream);
        prep_fb_kernel<<<ROPE_BLKS + TR_BLKS, 256, 0, stream>>>(Q, K, V, Qr, Kr, Vt);
        int chunks = 0;
        for (int i = 0; i < NQT; ++i) chunks += (2 * (i + 1) + CH_FB - 1) / CH_FB;
        attn_fb_kernel<<<NB * chunks, 256, 0, stream>>>(Qr, Kr, Vt, Out);
    }
}

// Round 16
// 28.770 us; speedup vs baseline: 3.6290x; 1.0808x over previous
//
#include <hip/hip_runtime.h>
#include <hip/hip_bf16.h>

#define S_LEN 4096
#define DIM   128
#define NB    4
#define L_CHUNK 128
#define NCH   (S_LEN / L_CHUNK)      // 32 chunks per batch
#define NHC   (2 * NCH)              // 64 half-chunks per batch
#define ROPE_BLKS (NB * S_LEN / 4)   // fallback prep blocks
#define TR_BLKS   (NB * S_LEN / 64)
#define NQT   (S_LEN / 256)          // fallback: 16 q-tiles per batch
#define CH_FB 3                      // fallback split-K

typedef __bf16 bf16_t;
typedef __attribute__((ext_vector_type(4)))  float        f32x4;
typedef __attribute__((ext_vector_type(8)))  __bf16       bf16x8;
typedef __attribute__((ext_vector_type(16))) float        f32x16;
typedef __attribute__((ext_vector_type(4)))  unsigned int u32x4;

#define MFMA32(a, b, c) __builtin_amdgcn_mfma_f32_32x32x16_bf16((a), (b), (c), 0, 0, 0)
#define CVTPK(d, a, b) asm("v_cvt_pk_bf16_f32 %0, %1, %2" : "=v"(d) : "v"(a), "v"(b))
// vdst HIGH lanes <-> vsrc LOW lanes (verified round 2)
#define PSWAP(d, s)    asm("v_permlane32_swap_b32 %0, %1" : "+v"(d), "+v"(s))

__device__ __forceinline__ unsigned swzo(int row, int colByte) {
    // 256B rows
    return (unsigned)(row * 256 + (colByte ^ ((row & 15) << 4)));
}
__device__ __forceinline__ unsigned swz64(int row, int colByte) {
    // 128B rows (64 bf16 per row)
    return (unsigned)(row * 128 + (colByte ^ ((row & 7) << 4)));
}

__device__ __forceinline__ void cvt_swap(const f32x16& s, unsigned int w[8]) {
    CVTPK(w[0], s[0],  s[1]);  CVTPK(w[1], s[2],  s[3]);
    CVTPK(w[2], s[4],  s[5]);  CVTPK(w[3], s[6],  s[7]);
    CVTPK(w[4], s[8],  s[9]);  CVTPK(w[5], s[10], s[11]);
    CVTPK(w[6], s[12], s[13]); CVTPK(w[7], s[14], s[15]);
    PSWAP(w[0], w[2]); PSWAP(w[1], w[3]);
    PSWAP(w[4], w[6]); PSWAP(w[5], w[7]);
}

__device__ __forceinline__ void ropesc(int seq, int i, float& cc, float& ss) {
    float ex      = -(float)i * (13.287712379549449f / 64.0f);
    float inv_rev = exp2f(ex) * 0.15915494309189535f;
    float rev = (float)seq * inv_rev;
    float fr  = rev - floorf(rev);
    cc = __builtin_amdgcn_cosf(fr);
    ss = __builtin_amdgcn_sinf(fr);
}

// ---------------- K1 (r12-verified mega_prep): rope Q,K + transpose-stage + G_half + Vt ----------------
__launch_bounds__(256, 2)
__global__ void mega_prep_kernel(const float* __restrict__ Q,
                                 const float* __restrict__ K,
                                 const float* __restrict__ V,
                                 bf16_t* __restrict__ Qr,
                                 bf16_t* __restrict__ Kr,
                                 bf16_t* __restrict__ Vt,
                                 bf16_t* __restrict__ Gh) {
    __shared__ bf16_t KsT[128 * 64];  // 16 KB [dk][k_loc], swz64
    __shared__ bf16_t VsT[128 * 64];  // 16 KB [dv][k_loc], swz64
    int b  = blockIdx.x >> 6;
    int hc = blockIdx.x & 63;
    int k0 = hc * 64;
    int tid = threadIdx.x, w = tid >> 6, lane = tid & 63;
    int lr = lane & 31, lg = lane >> 5;

    {
        int srow = tid >> 2;                 // 0..63 local row
        int j    = tid & 3;                  // col quarter
        int s    = k0 + srow;
        size_t base = ((size_t)b * S_LEN + s) * DIM;
        f32x4 ql[4], qh[4], kl[4], vl[4], vh[4], kh[4];
        #pragma unroll
        for (int u = 0; u < 4; ++u) {
            ql[u] = *(const f32x4*)(Q + base + 16 * j + 4 * u);
            qh[u] = *(const f32x4*)(Q + base + 64 + 16 * j + 4 * u);
            kl[u] = *(const f32x4*)(K + base + 16 * j + 4 * u);
            kh[u] = *(const f32x4*)(K + base + 64 + 16 * j + 4 * u);
            vl[u] = *(const f32x4*)(V + base + 16 * j + 4 * u);
            vh[u] = *(const f32x4*)(V + base + 64 + 16 * j + 4 * u);
        }
        bf16_t oql[16], oqh[16], okl[16], okh[16];
        #pragma unroll
        for (int e = 0; e < 16; ++e) {
            int i = 16 * j + e;
            float cc, ssn;
            ropesc(s, i, cc, ssn);
            float q1 = ql[e >> 2][e & 3], q2 = qh[e >> 2][e & 3];
            float k1 = kl[e >> 2][e & 3], k2 = kh[e >> 2][e & 3];
            oql[e] = (bf16_t)(q1 * cc - q2 * ssn);
            oqh[e] = (bf16_t)(q2 * cc + q1 * ssn);
            okl[e] = (bf16_t)(k1 * cc - k2 * ssn);
            okh[e] = (bf16_t)(k2 * cc + k1 * ssn);
        }
        #pragma unroll
        for (int hlf = 0; hlf < 2; ++hlf) {
            *(bf16x8*)(Qr + base + 16 * j + 8 * hlf)      = *(bf16x8*)&oql[8 * hlf];
            *(bf16x8*)(Qr + base + 64 + 16 * j + 8 * hlf) = *(bf16x8*)&oqh[8 * hlf];
            *(bf16x8*)(Kr + base + 16 * j + 8 * hlf)      = *(bf16x8*)&okl[8 * hlf];
            *(bf16x8*)(Kr + base + 64 + 16 * j + 8 * hlf) = *(bf16x8*)&okh[8 * hlf];
        }
        #pragma unroll
        for (int e = 0; e < 16; ++e) {
            int dk = 16 * j + e;
            *(bf16_t*)((char*)KsT + swz64(dk,      srow * 2)) = okl[e];
            *(bf16_t*)((char*)KsT + swz64(dk + 64, srow * 2)) = okh[e];
            *(bf16_t*)((char*)VsT + swz64(dk,      srow * 2)) = (bf16_t)vl[e >> 2][e & 3];
            *(bf16_t*)((char*)VsT + swz64(dk + 64, srow * 2)) = (bf16_t)vh[e >> 2][e & 3];
        }
    }
    __syncthreads();

    f32x16 acc[4];
    #pragma unroll
    for (int db = 0; db < 4; ++db)
        #pragma unroll
        for (int r = 0; r < 16; ++r) acc[db][r] = 0.f;

    #pragma unroll
    for (int sI = 0; sI < 4; ++sI) {
        bf16x8 af = *(const bf16x8*)((const char*)VsT +
            swz64(32 * w + lr, (sI * 16 + lg * 8) * 2));
        #pragma unroll
        for (int db = 0; db < 4; ++db) {
            bf16x8 bfr = *(const bf16x8*)((const char*)KsT +
                swz64(32 * db + lr, (sI * 16 + lg * 8) * 2));
            acc[db] = MFMA32(af, bfr, acc[db]);
        }
    }
    bf16_t* Gc = Gh + ((size_t)b * NHC + hc) * DIM * DIM;
    #pragma unroll
    for (int db = 0; db < 4; ++db)
        #pragma unroll
        for (int r = 0; r < 16; ++r) {
            int dv = 32 * w + (r & 3) + ((r >> 2) << 3) + (lg << 2);
            Gc[(size_t)dv * DIM + 32 * db + lr] = (bf16_t)acc[db][r];
        }

    #pragma unroll
    for (int m = 0; m < 4; ++m) {
        int idx  = tid + 256 * m;            // 0..1023
        int dv   = idx >> 3;
        int slot = idx & 7;
        bf16x8 v = *(const bf16x8*)((const char*)VsT + swz64(dv, slot * 16));
        *(bf16x8*)(Vt + ((size_t)b * DIM + dv) * S_LEN + k0 + slot * 8) = v;
    }
}

// ---------------- K2 (r12-verified): exclusive prefix over 64 halves -> Gp ----------------
__global__ void stage2_kernel(const bf16_t* __restrict__ Gh, bf16_t* __restrict__ Gp) {
    int b = blockIdx.x >> 6;
    int p = (blockIdx.x & 63) * 128 + threadIdx.x;   // pair index [0,8192)
    const bf16_t* ph = Gh + (size_t)b * NHC * DIM * DIM + (size_t)p * 2;
    bf16_t* pp = Gp + (size_t)b * NCH * DIM * DIM + (size_t)p * 2;
    float rlo = 0.f, rhi = 0.f;
    #pragma unroll
    for (int c = 0; c < NCH; ++c) {
        unsigned s = (unsigned)__builtin_bit_cast(unsigned short, (bf16_t)rlo) |
                     ((unsigned)__builtin_bit_cast(unsigned short, (bf16_t)rhi) << 16);
        *(unsigned*)(pp + (size_t)c * DIM * DIM) = s;
        unsigned u0 = *(const unsigned*)(ph + (size_t)(2 * c) * DIM * DIM);
        unsigned u1 = *(const unsigned*)(ph + (size_t)(2 * c + 1) * DIM * DIM);
        rlo += __builtin_bit_cast(float, u0 << 16) + __builtin_bit_cast(float, u1 << 16);
        rhi += __builtin_bit_cast(float, u0 & 0xffff0000u) +
               __builtin_bit_cast(float, u1 & 0xffff0000u);
    }
}

// ---------------- K3 (r12-verified body + XCD pair-swizzle): O = Q*Gp + tril(Q Kc^T) Vc ----------------
__launch_bounds__(256, 1)
__global__ void stage3_kernel(const bf16_t* __restrict__ Qr,
                              const bf16_t* __restrict__ Kr,
                              const bf16_t* __restrict__ Vt,
                              const bf16_t* __restrict__ Gp,
                              float* __restrict__ Out) {
    __shared__ bf16_t Ks[128 * 128];  // 32 KB full K chunk [k][d]
    __shared__ bf16_t Vs[64 * 128];   // 16 KB [dv-local][k]
    // pair-swizzle: bid = 16k + 8m + j  ->  chunk p = 8k+j, dh = m.
    // Both members of a (c,dh) pair have bid ≡ j (mod 8) -> same XCD -> shared
    // Ks (32KB Kr chunk) L2-hits on the second read. Bijective by construction.
    int bid = blockIdx.x;
    int p   = ((bid >> 4) << 3) | (bid & 7);   // 0..127
    int dh  = (bid >> 3) & 1;
    int b   = p >> 5;
    int c   = p & 31;
    int tid = threadIdx.x, w = tid >> 6, lane = tid & 63;
    int lr = lane & 31, lg = lane >> 5;
    int q0 = c * L_CHUNK;
    const bf16_t* Qb = Qr + (size_t)b * S_LEN * DIM;
    const bf16_t* Kb = Kr + (size_t)b * S_LEN * DIM;
    const bf16_t* Vb = Vt + (size_t)b * DIM * S_LEN;
    const bf16_t* Gb = Gp + ((size_t)b * NCH + c) * DIM * DIM;

    bf16x8 qf[8];
    #pragma unroll
    for (int s2 = 0; s2 < 8; ++s2)
        qf[s2] = *(const bf16x8*)(Qb + (size_t)(q0 + 32 * w + lr) * DIM
                                  + s2 * 16 + lg * 8);

    #pragma unroll
    for (int j = 0; j < 8; ++j) {
        int idx = tid + j * 256;
        int row = idx >> 4, slot = idx & 15;
        u32x4 kd = *(const u32x4*)(Kb + (size_t)(q0 + row) * DIM + slot * 8);
        *(u32x4*)((char*)Ks + swzo(row, slot * 16)) = kd;
    }
    #pragma unroll
    for (int j = 0; j < 4; ++j) {
        int idx = tid + j * 256;            // row in [0,64)
        int row = idx >> 4, slot = idx & 15;
        u32x4 vd = *(const u32x4*)(Vb + (size_t)(64 * dh + row) * S_LEN + q0 + slot * 8);
        *(u32x4*)((char*)Vs + swzo(row, slot * 16)) = vd;
    }
    __syncthreads();

    f32x16 acc[2];
    #pragma unroll
    for (int i = 0; i < 2; ++i)
        #pragma unroll
        for (int r = 0; r < 16; ++r) acc[i][r] = 0.f;

    // part A: O += Q . G_pre ; G-fragments direct from global (dv in this d-half)
    if (c > 0) {
        #pragma unroll
        for (int s2 = 0; s2 < 8; ++s2) {
            #pragma unroll
            for (int i = 0; i < 2; ++i) {
                bf16x8 gfr = *(const bf16x8*)(Gb +
                    (size_t)(64 * dh + 32 * i + lr) * DIM + s2 * 16 + lg * 8);
                acc[i] = MFMA32(qf[s2], gfr, acc[i]);
            }
        }
    }

    // intra: causal within the diagonal chunk (swapped QK^T, cvt_pk+permlane P)
    for (int g = 0; g <= w; ++g) {
        int ksub = g * 32;
        f32x16 sa;
        #pragma unroll
        for (int r = 0; r < 16; ++r) sa[r] = 0.f;
        #pragma unroll
        for (int s2 = 0; s2 < 8; ++s2) {
            bf16x8 af = *(const bf16x8*)((const char*)Ks +
                swzo(ksub + lr, (s2 * 16 + lg * 8) * 2));
            sa = MFMA32(af, qf[s2], sa);
        }
        if (g == w) {
            #pragma unroll
            for (int r = 0; r < 16; ++r) {
                int crow = (r & 3) + ((r >> 2) << 3) + (lg << 2);
                sa[r] = (crow > lr) ? 0.f : sa[r];
            }
        }
        unsigned int wv[8];
        cvt_swap(sa, wv);
        u32x4 tA = {wv[0], wv[1], wv[2], wv[3]};
        u32x4 tB = {wv[4], wv[5], wv[6], wv[7]};
        bf16x8 pA = __builtin_bit_cast(bf16x8, tA);
        bf16x8 pB = __builtin_bit_cast(bf16x8, tB);
        #pragma unroll
        for (int i = 0; i < 2; ++i) {
            bf16x8 v0 = *(const bf16x8*)((const char*)Vs +
                swzo(32 * i + lr, (ksub + lg * 8) * 2));
            bf16x8 v1 = *(const bf16x8*)((const char*)Vs +
                swzo(32 * i + lr, (ksub + 16 + lg * 8) * 2));
            acc[i] = MFMA32(pA, v0, acc[i]);
            acc[i] = MFMA32(pB, v1, acc[i]);
        }
    }

    float* Ob = Out + (size_t)b * S_LEN * DIM;
    #pragma unroll
    for (int i = 0; i < 2; ++i)
        #pragma unroll
        for (int r = 0; r < 16; ++r) {
            int q = q0 + 32 * w + (r & 3) + ((r >> 2) << 3) + (lg << 2);
            int d = 64 * dh + 32 * i + lr;
            Ob[(size_t)q * DIM + d] = acc[i][r];
        }
}

// ---------------- fallback path (small ws): r2-verified prep + atomic kernel ----------------
__global__ void prep_fb_kernel(const float* __restrict__ Q,
                               const float* __restrict__ K,
                               const float* __restrict__ V,
                               bf16_t* __restrict__ Qr,
                               bf16_t* __restrict__ Kr,
                               bf16_t* __restrict__ Vt) {
    int bid = blockIdx.x;
    int t   = threadIdx.x;
    if (bid < ROPE_BLKS) {
        int i   = t & 63;
        int row = bid * 4 + (t >> 6);
        int s   = row & (S_LEN - 1);
        size_t base = (size_t)row * DIM;
        float cc, ssn;
        ropesc(s, i, cc, ssn);
        float q1 = Q[base + i], q2 = Q[base + i + 64];
        float k1 = K[base + i], k2 = K[base + i + 64];
        Qr[base + i]      = (bf16_t)(q1 * cc - q2 * ssn);
        Qr[base + i + 64] = (bf16_t)(q2 * cc + q1 * ssn);
        Kr[base + i]      = (bf16_t)(k1 * cc - k2 * ssn);
        Kr[base + i + 64] = (bf16_t)(k2 * cc + k1 * ssn);
    } else {
        int idx = bid - ROPE_BLKS;
        int b   = idx >> 6;
        int s0  = (idx & 63) * 64;
        int d   = t >> 1;
        int sh  = (t & 1) * 32;
        const float* vb = V + (size_t)b * S_LEN * DIM;
        bf16_t* ob = Vt + ((size_t)b * DIM + d) * S_LEN;
        #pragma unroll
        for (int j8 = 0; j8 < 4; ++j8) {
            bf16x8 u;
            #pragma unroll
            for (int e2 = 0; e2 < 8; ++e2) {
                int s = s0 + sh + j8 * 8 + e2;
                u[e2] = (bf16_t)vb[(size_t)s * DIM + d];
            }
            *(bf16x8*)(ob + s0 + sh + j8 * 8) = u;
        }
    }
}

__launch_bounds__(256, 2)
__global__ void attn_fb_kernel(const bf16_t* __restrict__ Qr,
                               const bf16_t* __restrict__ Kr,
                               const bf16_t* __restrict__ Vt,
                               float* __restrict__ Out) {
    __shared__ bf16_t Kt[128 * 128];
    __shared__ bf16_t Vl[128 * 128];
    int b = blockIdx.x & 3;
    int t = blockIdx.x >> 2;
    int qt = 0, c0 = 0;
    for (int i2 = NQT - 1; i2 >= 0; --i2) {
        int n = (2 * (i2 + 1) + CH_FB - 1) / CH_FB;
        if (t < n) { qt = i2; c0 = t; break; }
        t -= n;
    }
    int nkt   = 2 * (qt + 1);
    int kt_lo = c0 * CH_FB;
    int kt_hi = min(kt_lo + CH_FB, nkt);
    bool single = ((nkt + CH_FB - 1) / CH_FB) == 1;

    int tid = threadIdx.x, w = tid >> 6, lane = tid & 63;
    int lr = lane & 31, lg = lane >> 5;
    int qw = qt * 256 + w * 64;
    const bf16_t* Qb = Qr + (size_t)b * S_LEN * DIM;
    const bf16_t* Kb = Kr + (size_t)b * S_LEN * DIM;
    const bf16_t* Vb = Vt + (size_t)b * DIM * S_LEN;

    bf16x8 qf[2][8];
    #pragma unroll
    for (int qb = 0; qb < 2; ++qb)
        #pragma unroll
        for (int s2 = 0; s2 < 8; ++s2)
            qf[qb][s2] = *(const bf16x8*)(Qb + (size_t)(qw + qb * 32 + lr) * DIM
                                          + s2 * 16 + lg * 8);
    f32x16 acc[2][4];
    #pragma unroll
    for (int qb = 0; qb < 2; ++qb)
        #pragma unroll
        for (int db = 0; db < 4; ++db)
            #pragma unroll
            for (int r = 0; r < 16; ++r) acc[qb][db][r] = 0.f;

    for (int kt = kt_lo; kt < kt_hi; ++kt) {
        int kbase = kt * 128;
        #pragma unroll
        for (int j = 0; j < 8; ++j) {
            int idx = tid + j * 256;
            int row = idx >> 4, slot = idx & 15;
            u32x4 kd = *(const u32x4*)(Kb + (size_t)(kbase + row) * DIM + slot * 8);
            *(u32x4*)((char*)Kt + swzo(row, slot * 16)) = kd;
            u32x4 vd = *(const u32x4*)(Vb + (size_t)row * S_LEN + kbase + slot * 8);
            *(u32x4*)((char*)Vl + swzo(row, slot * 16)) = vd;
        }
        __syncthreads();
        #pragma unroll
        for (int kb = 0; kb < 4; ++kb) {
            int ksub = kb * 32;
            int kmin = kbase + ksub;
            if (kmin > qw + 63) break;
            bool do0 = (kmin <= qw + 31);
            f32x16 s0, s1;
            #pragma unroll
            for (int r = 0; r < 16; ++r) { s0[r] = 0.f; s1[r] = 0.f; }
            #pragma unroll
            for (int h = 0; h < 2; ++h) {
                bf16x8 af[4];
                #pragma unroll
                for (int s2 = 0; s2 < 4; ++s2)
                    af[s2] = *(const bf16x8*)((const char*)Kt +
                        swzo(ksub + lr, (h * 64 + s2 * 16 + lg * 8) * 2));
                #pragma unroll
                for (int s2 = 0; s2 < 4; ++s2) {
                    if (do0) s0 = MFMA32(af[s2], qf[0][h * 4 + s2], s0);
                    s1 = MFMA32(af[s2], qf[1][h * 4 + s2], s1);
                }
            }
            if (kmin + 31 > qw) {
                #pragma unroll
                for (int r = 0; r < 16; ++r) {
                    int kg = kmin + (r & 3) + ((r >> 2) << 3) + (lg << 2);
                    s0[r] = (kg > qw + lr)      ? 0.f : s0[r];
                    s1[r] = (kg > qw + 32 + lr) ? 0.f : s1[r];
                }
            }
            unsigned int w0[8], w1[8];
            cvt_swap(s0, w0);
            cvt_swap(s1, w1);
            u32x4 t00 = {w0[0], w0[1], w0[2], w0[3]};
            u32x4 t01 = {w0[4], w0[5], w0[6], w0[7]};
            u32x4 t10 = {w1[0], w1[1], w1[2], w1[3]};
            u32x4 t11 = {w1[4], w1[5], w1[6], w1[7]};
            bf16x8 p00 = __builtin_bit_cast(bf16x8, t00);
            bf16x8 p01 = __builtin_bit_cast(bf16x8, t01);
            bf16x8 p10 = __builtin_bit_cast(bf16x8, t10);
            bf16x8 p11 = __builtin_bit_cast(bf16x8, t11);
            #pragma unroll
            for (int db = 0; db < 4; ++db) {
                bf16x8 vb0 = *(const bf16x8*)((const char*)Vl +
                    swzo(db * 32 + lr, (ksub + lg * 8) * 2));
                bf16x8 vb1 = *(const bf16x8*)((const char*)Vl +
                    swzo(db * 32 + lr, (ksub + 16 + lg * 8) * 2));
                if (do0) {
                    acc[0][db] = MFMA32(p00, vb0, acc[0][db]);
                    acc[0][db] = MFMA32(p01, vb1, acc[0][db]);
                }
                acc[1][db] = MFMA32(p10, vb0, acc[1][db]);
                acc[1][db] = MFMA32(p11, vb1, acc[1][db]);
            }
        }
        __syncthreads();
    }
    float* Ob = Out + (size_t)b * S_LEN * DIM;
    #pragma unroll
    for (int qb = 0; qb < 2; ++qb)
        #pragma unroll
        for (int db = 0; db < 4; ++db)
            #pragma unroll
            for (int r = 0; r < 16; ++r) {
                int q = qw + qb * 32 + (r & 3) + ((r >> 2) << 3) + (lg << 2);
                int d = db * 32 + lr;
                float v = acc[qb][db][r];
                float* p = Ob + (size_t)q * DIM + d;
                if (single) *p = v; else atomicAdd(p, v);
            }
}

extern "C" void kernel_launch(void* const* d_in, const int* in_sizes, int n_in,
                              void* d_out, int out_size, void* d_ws, size_t ws_size,
                              hipStream_t stream) {
    const float* Q = (const float*)d_in[0];
    const float* K = (const float*)d_in[1];
    const float* V = (const float*)d_in[2];
    float* Out = (float*)d_out;

    size_t plane  = (size_t)NB * S_LEN * DIM * sizeof(bf16_t);         // 4 MB
    size_t ghalf  = (size_t)NB * NHC * DIM * DIM * sizeof(bf16_t);     // 8 MB
    size_t gpre   = (size_t)NB * NCH * DIM * DIM * sizeof(bf16_t);     // 4 MB
    char* wsb = (char*)d_ws;

    if (ws_size >= 3 * plane + ghalf + gpre) {
        bf16_t* Qr = (bf16_t*)wsb;
        bf16_t* Kr = (bf16_t*)(wsb + plane);
        bf16_t* Vt = (bf16_t*)(wsb + 2 * plane);
        bf16_t* Gh = (bf16_t*)(wsb + 3 * plane);
        bf16_t* Gp = (bf16_t*)(wsb + 3 * plane + ghalf);
        mega_prep_kernel<<<NB * NHC, 256, 0, stream>>>(Q, K, V, Qr, Kr, Vt, Gh);
        stage2_kernel<<<NB * 64, 128, 0, stream>>>(Gh, Gp);
        stage3_kernel<<<NB * NCH * 2, 256, 0, stream>>>(Qr, Kr, Vt, Gp, Out);
    } else if (ws_size >= 3 * plane) {
        bf16_t* Qr = (bf16_t*)wsb;
        bf16_t* Kr = (bf16_t*)(wsb + plane);
        bf16_t* Vt = (bf16_t*)(wsb + 2 * plane);
        hipMemsetAsync(d_out, 0, (size_t)NB * S_LEN * DIM * sizeof(float), stream);
        prep_fb_kernel<<<ROPE_BLKS + TR_BLKS, 256, 0, stream>>>(Q, K, V, Qr, Kr, Vt);
        int chunks = 0;
        for (int i = 0; i < NQT; ++i) chunks += (2 * (i + 1) + CH_FB - 1) / CH_FB;
        attn_fb_kernel<<<NB * chunks, 256, 0, stream>>>(Qr, Kr, Vt, Out);
    }
}

// Round 17
// 28.077 us; speedup vs baseline: 3.7186x; 1.0247x over previous
//
#include <hip/hip_runtime.h>
#include <hip/hip_bf16.h>

#define S_LEN 4096
#define DIM   128
#define NB    4
#define L_CHUNK 128
#define NCH   (S_LEN / L_CHUNK)      // 32 chunks per batch
#define NHC   (2 * NCH)              // 64 half-chunks per batch
#define ROPE_BLKS (NB * S_LEN / 4)   // fallback prep blocks
#define TR_BLKS   (NB * S_LEN / 64)
#define NQT   (S_LEN / 256)          // fallback: 16 q-tiles per batch
#define CH_FB 3                      // fallback split-K

typedef __bf16 bf16_t;
typedef __attribute__((ext_vector_type(4)))  float        f32x4;
typedef __attribute__((ext_vector_type(8)))  __bf16       bf16x8;
typedef __attribute__((ext_vector_type(16))) float        f32x16;
typedef __attribute__((ext_vector_type(4)))  unsigned int u32x4;

#define MFMA32(a, b, c) __builtin_amdgcn_mfma_f32_32x32x16_bf16((a), (b), (c), 0, 0, 0)
#define CVTPK(d, a, b) asm("v_cvt_pk_bf16_f32 %0, %1, %2" : "=v"(d) : "v"(a), "v"(b))
// vdst HIGH lanes <-> vsrc LOW lanes (verified round 2)
#define PSWAP(d, s)    asm("v_permlane32_swap_b32 %0, %1" : "+v"(d), "+v"(s))

__device__ __forceinline__ unsigned swzo(int row, int colByte) {
    // 256B rows
    return (unsigned)(row * 256 + (colByte ^ ((row & 15) << 4)));
}
__device__ __forceinline__ unsigned swz64(int row, int colByte) {
    // 128B rows (64 bf16 per row)
    return (unsigned)(row * 128 + (colByte ^ ((row & 7) << 4)));
}

__device__ __forceinline__ void cvt_swap(const f32x16& s, unsigned int w[8]) {
    CVTPK(w[0], s[0],  s[1]);  CVTPK(w[1], s[2],  s[3]);
    CVTPK(w[2], s[4],  s[5]);  CVTPK(w[3], s[6],  s[7]);
    CVTPK(w[4], s[8],  s[9]);  CVTPK(w[5], s[10], s[11]);
    CVTPK(w[6], s[12], s[13]); CVTPK(w[7], s[14], s[15]);
    PSWAP(w[0], w[2]); PSWAP(w[1], w[3]);
    PSWAP(w[4], w[6]); PSWAP(w[5], w[7]);
}

__device__ __forceinline__ void ropesc(int seq, int i, float& cc, float& ss) {
    float ex      = -(float)i * (13.287712379549449f / 64.0f);
    float inv_rev = exp2f(ex) * 0.15915494309189535f;
    float rev = (float)seq * inv_rev;
    float fr  = rev - floorf(rev);
    cc = __builtin_amdgcn_cosf(fr);
    ss = __builtin_amdgcn_sinf(fr);
}

// ---------------- K1 (r12-verified mega_prep): rope Q,K + transpose-stage + G_half + Vt ----------------
__launch_bounds__(256, 2)
__global__ void mega_prep_kernel(const float* __restrict__ Q,
                                 const float* __restrict__ K,
                                 const float* __restrict__ V,
                                 bf16_t* __restrict__ Qr,
                                 bf16_t* __restrict__ Kr,
                                 bf16_t* __restrict__ Vt,
                                 bf16_t* __restrict__ Gh) {
    __shared__ bf16_t KsT[128 * 64];  // 16 KB [dk][k_loc], swz64
    __shared__ bf16_t VsT[128 * 64];  // 16 KB [dv][k_loc], swz64
    int b  = blockIdx.x >> 6;
    int hc = blockIdx.x & 63;
    int k0 = hc * 64;
    int tid = threadIdx.x, w = tid >> 6, lane = tid & 63;
    int lr = lane & 31, lg = lane >> 5;

    {
        int srow = tid >> 2;                 // 0..63 local row
        int j    = tid & 3;                  // col quarter
        int s    = k0 + srow;
        size_t base = ((size_t)b * S_LEN + s) * DIM;
        f32x4 ql[4], qh[4], kl[4], vl[4], vh[4], kh[4];
        #pragma unroll
        for (int u = 0; u < 4; ++u) {
            ql[u] = *(const f32x4*)(Q + base + 16 * j + 4 * u);
            qh[u] = *(const f32x4*)(Q + base + 64 + 16 * j + 4 * u);
            kl[u] = *(const f32x4*)(K + base + 16 * j + 4 * u);
            kh[u] = *(const f32x4*)(K + base + 64 + 16 * j + 4 * u);
            vl[u] = *(const f32x4*)(V + base + 16 * j + 4 * u);
            vh[u] = *(const f32x4*)(V + base + 64 + 16 * j + 4 * u);
        }
        bf16_t oql[16], oqh[16], okl[16], okh[16];
        #pragma unroll
        for (int e = 0; e < 16; ++e) {
            int i = 16 * j + e;
            float cc, ssn;
            ropesc(s, i, cc, ssn);
            float q1 = ql[e >> 2][e & 3], q2 = qh[e >> 2][e & 3];
            float k1 = kl[e >> 2][e & 3], k2 = kh[e >> 2][e & 3];
            oql[e] = (bf16_t)(q1 * cc - q2 * ssn);
            oqh[e] = (bf16_t)(q2 * cc + q1 * ssn);
            okl[e] = (bf16_t)(k1 * cc - k2 * ssn);
            okh[e] = (bf16_t)(k2 * cc + k1 * ssn);
        }
        #pragma unroll
        for (int hlf = 0; hlf < 2; ++hlf) {
            *(bf16x8*)(Qr + base + 16 * j + 8 * hlf)      = *(bf16x8*)&oql[8 * hlf];
            *(bf16x8*)(Qr + base + 64 + 16 * j + 8 * hlf) = *(bf16x8*)&oqh[8 * hlf];
            *(bf16x8*)(Kr + base + 16 * j + 8 * hlf)      = *(bf16x8*)&okl[8 * hlf];
            *(bf16x8*)(Kr + base + 64 + 16 * j + 8 * hlf) = *(bf16x8*)&okh[8 * hlf];
        }
        #pragma unroll
        for (int e = 0; e < 16; ++e) {
            int dk = 16 * j + e;
            *(bf16_t*)((char*)KsT + swz64(dk,      srow * 2)) = okl[e];
            *(bf16_t*)((char*)KsT + swz64(dk + 64, srow * 2)) = okh[e];
            *(bf16_t*)((char*)VsT + swz64(dk,      srow * 2)) = (bf16_t)vl[e >> 2][e & 3];
            *(bf16_t*)((char*)VsT + swz64(dk + 64, srow * 2)) = (bf16_t)vh[e >> 2][e & 3];
        }
    }
    __syncthreads();

    f32x16 acc[4];
    #pragma unroll
    for (int db = 0; db < 4; ++db)
        #pragma unroll
        for (int r = 0; r < 16; ++r) acc[db][r] = 0.f;

    #pragma unroll
    for (int sI = 0; sI < 4; ++sI) {
        bf16x8 af = *(const bf16x8*)((const char*)VsT +
            swz64(32 * w + lr, (sI * 16 + lg * 8) * 2));
        #pragma unroll
        for (int db = 0; db < 4; ++db) {
            bf16x8 bfr = *(const bf16x8*)((const char*)KsT +
                swz64(32 * db + lr, (sI * 16 + lg * 8) * 2));
            acc[db] = MFMA32(af, bfr, acc[db]);
        }
    }
    bf16_t* Gc = Gh + ((size_t)b * NHC + hc) * DIM * DIM;
    #pragma unroll
    for (int db = 0; db < 4; ++db)
        #pragma unroll
        for (int r = 0; r < 16; ++r) {
            int dv = 32 * w + (r & 3) + ((r >> 2) << 3) + (lg << 2);
            Gc[(size_t)dv * DIM + 32 * db + lr] = (bf16_t)acc[db][r];
        }

    #pragma unroll
    for (int m = 0; m < 4; ++m) {
        int idx  = tid + 256 * m;            // 0..1023
        int dv   = idx >> 3;
        int slot = idx & 7;
        bf16x8 v = *(const bf16x8*)((const char*)VsT + swz64(dv, slot * 16));
        *(bf16x8*)(Vt + ((size_t)b * DIM + dv) * S_LEN + k0 + slot * 8) = v;
    }
}

// ---------------- K2: exclusive prefix over 64 halves -> Gp (loads hoisted, same math) ----------------
__global__ void stage2_kernel(const bf16_t* __restrict__ Gh, bf16_t* __restrict__ Gp) {
    int b = blockIdx.x >> 6;
    int p = (blockIdx.x & 63) * 128 + threadIdx.x;   // pair index [0,8192)
    const bf16_t* ph = Gh + (size_t)b * NHC * DIM * DIM + (size_t)p * 2;
    bf16_t* pp = Gp + (size_t)b * NCH * DIM * DIM + (size_t)p * 2;
    // issue all 64 independent loads first (one latency epoch), then scan in regs
    unsigned uv[64];
    #pragma unroll
    for (int h = 0; h < 64; ++h)
        uv[h] = *(const unsigned*)(ph + (size_t)h * DIM * DIM);
    float rlo = 0.f, rhi = 0.f;
    unsigned outv[32];
    #pragma unroll
    for (int c = 0; c < NCH; ++c) {
        outv[c] = (unsigned)__builtin_bit_cast(unsigned short, (bf16_t)rlo) |
                  ((unsigned)__builtin_bit_cast(unsigned short, (bf16_t)rhi) << 16);
        unsigned u0 = uv[2 * c], u1 = uv[2 * c + 1];
        rlo += __builtin_bit_cast(float, u0 << 16) + __builtin_bit_cast(float, u1 << 16);
        rhi += __builtin_bit_cast(float, u0 & 0xffff0000u) +
               __builtin_bit_cast(float, u1 & 0xffff0000u);
    }
    #pragma unroll
    for (int c = 0; c < NCH; ++c)
        *(unsigned*)(pp + (size_t)c * DIM * DIM) = outv[c];
}

// ---------------- K3 (r16-verified): O = Q*Gp + tril(Q Kc^T) Vc, XCD pair-swizzle ----------------
__launch_bounds__(256, 1)
__global__ void stage3_kernel(const bf16_t* __restrict__ Qr,
                              const bf16_t* __restrict__ Kr,
                              const bf16_t* __restrict__ Vt,
                              const bf16_t* __restrict__ Gp,
                              float* __restrict__ Out) {
    __shared__ bf16_t Ks[128 * 128];  // 32 KB full K chunk [k][d]
    __shared__ bf16_t Vs[64 * 128];   // 16 KB [dv-local][k]
    // pair-swizzle: bid = 16k + 8m + j -> chunk p = 8k+j, dh = m (same-XCD pairs)
    int bid = blockIdx.x;
    int p   = ((bid >> 4) << 3) | (bid & 7);   // 0..127
    int dh  = (bid >> 3) & 1;
    int b   = p >> 5;
    int c   = p & 31;
    int tid = threadIdx.x, w = tid >> 6, lane = tid & 63;
    int lr = lane & 31, lg = lane >> 5;
    int q0 = c * L_CHUNK;
    const bf16_t* Qb = Qr + (size_t)b * S_LEN * DIM;
    const bf16_t* Kb = Kr + (size_t)b * S_LEN * DIM;
    const bf16_t* Vb = Vt + (size_t)b * DIM * S_LEN;
    const bf16_t* Gb = Gp + ((size_t)b * NCH + c) * DIM * DIM;

    bf16x8 qf[8];
    #pragma unroll
    for (int s2 = 0; s2 < 8; ++s2)
        qf[s2] = *(const bf16x8*)(Qb + (size_t)(q0 + 32 * w + lr) * DIM
                                  + s2 * 16 + lg * 8);

    #pragma unroll
    for (int j = 0; j < 8; ++j) {
        int idx = tid + j * 256;
        int row = idx >> 4, slot = idx & 15;
        u32x4 kd = *(const u32x4*)(Kb + (size_t)(q0 + row) * DIM + slot * 8);
        *(u32x4*)((char*)Ks + swzo(row, slot * 16)) = kd;
    }
    #pragma unroll
    for (int j = 0; j < 4; ++j) {
        int idx = tid + j * 256;            // row in [0,64)
        int row = idx >> 4, slot = idx & 15;
        u32x4 vd = *(const u32x4*)(Vb + (size_t)(64 * dh + row) * S_LEN + q0 + slot * 8);
        *(u32x4*)((char*)Vs + swzo(row, slot * 16)) = vd;
    }
    __syncthreads();

    f32x16 acc[2];
    #pragma unroll
    for (int i = 0; i < 2; ++i)
        #pragma unroll
        for (int r = 0; r < 16; ++r) acc[i][r] = 0.f;

    // part A: O += Q . G_pre ; G-fragments direct from global (dv in this d-half)
    if (c > 0) {
        #pragma unroll
        for (int s2 = 0; s2 < 8; ++s2) {
            #pragma unroll
            for (int i = 0; i < 2; ++i) {
                bf16x8 gfr = *(const bf16x8*)(Gb +
                    (size_t)(64 * dh + 32 * i + lr) * DIM + s2 * 16 + lg * 8);
                acc[i] = MFMA32(qf[s2], gfr, acc[i]);
            }
        }
    }

    // intra: causal within the diagonal chunk (swapped QK^T, cvt_pk+permlane P)
    for (int g = 0; g <= w; ++g) {
        int ksub = g * 32;
        f32x16 sa;
        #pragma unroll
        for (int r = 0; r < 16; ++r) sa[r] = 0.f;
        #pragma unroll
        for (int s2 = 0; s2 < 8; ++s2) {
            bf16x8 af = *(const bf16x8*)((const char*)Ks +
                swzo(ksub + lr, (s2 * 16 + lg * 8) * 2));
            sa = MFMA32(af, qf[s2], sa);
        }
        if (g == w) {
            #pragma unroll
            for (int r = 0; r < 16; ++r) {
                int crow = (r & 3) + ((r >> 2) << 3) + (lg << 2);
                sa[r] = (crow > lr) ? 0.f : sa[r];
            }
        }
        unsigned int wv[8];
        cvt_swap(sa, wv);
        u32x4 tA = {wv[0], wv[1], wv[2], wv[3]};
        u32x4 tB = {wv[4], wv[5], wv[6], wv[7]};
        bf16x8 pA = __builtin_bit_cast(bf16x8, tA);
        bf16x8 pB = __builtin_bit_cast(bf16x8, tB);
        #pragma unroll
        for (int i = 0; i < 2; ++i) {
            bf16x8 v0 = *(const bf16x8*)((const char*)Vs +
                swzo(32 * i + lr, (ksub + lg * 8) * 2));
            bf16x8 v1 = *(const bf16x8*)((const char*)Vs +
                swzo(32 * i + lr, (ksub + 16 + lg * 8) * 2));
            acc[i] = MFMA32(pA, v0, acc[i]);
            acc[i] = MFMA32(pB, v1, acc[i]);
        }
    }

    float* Ob = Out + (size_t)b * S_LEN * DIM;
    #pragma unroll
    for (int i = 0; i < 2; ++i)
        #pragma unroll
        for (int r = 0; r < 16; ++r) {
            int q = q0 + 32 * w + (r & 3) + ((r >> 2) << 3) + (lg << 2);
            int d = 64 * dh + 32 * i + lr;
            Ob[(size_t)q * DIM + d] = acc[i][r];
        }
}

// ---------------- fallback path (small ws): r2-verified prep + atomic kernel ----------------
__global__ void prep_fb_kernel(const float* __restrict__ Q,
                               const float* __restrict__ K,
                               const float* __restrict__ V,
                               bf16_t* __restrict__ Qr,
                               bf16_t* __restrict__ Kr,
                               bf16_t* __restrict__ Vt) {
    int bid = blockIdx.x;
    int t   = threadIdx.x;
    if (bid < ROPE_BLKS) {
        int i   = t & 63;
        int row = bid * 4 + (t >> 6);
        int s   = row & (S_LEN - 1);
        size_t base = (size_t)row * DIM;
        float cc, ssn;
        ropesc(s, i, cc, ssn);
        float q1 = Q[base + i], q2 = Q[base + i + 64];
        float k1 = K[base + i], k2 = K[base + i + 64];
        Qr[base + i]      = (bf16_t)(q1 * cc - q2 * ssn);
        Qr[base + i + 64] = (bf16_t)(q2 * cc + q1 * ssn);
        Kr[base + i]      = (bf16_t)(k1 * cc - k2 * ssn);
        Kr[base + i + 64] = (bf16_t)(k2 * cc + k1 * ssn);
    } else {
        int idx = bid - ROPE_BLKS;
        int b   = idx >> 6;
        int s0  = (idx & 63) * 64;
        int d   = t >> 1;
        int sh  = (t & 1) * 32;
        const float* vb = V + (size_t)b * S_LEN * DIM;
        bf16_t* ob = Vt + ((size_t)b * DIM + d) * S_LEN;
        #pragma unroll
        for (int j8 = 0; j8 < 4; ++j8) {
            bf16x8 u;
            #pragma unroll
            for (int e2 = 0; e2 < 8; ++e2) {
                int s = s0 + sh + j8 * 8 + e2;
                u[e2] = (bf16_t)vb[(size_t)s * DIM + d];
            }
            *(bf16x8*)(ob + s0 + sh + j8 * 8) = u;
        }
    }
}

__launch_bounds__(256, 2)
__global__ void attn_fb_kernel(const bf16_t* __restrict__ Qr,
                               const bf16_t* __restrict__ Kr,
                               const bf16_t* __restrict__ Vt,
                               float* __restrict__ Out) {
    __shared__ bf16_t Kt[128 * 128];
    __shared__ bf16_t Vl[128 * 128];
    int b = blockIdx.x & 3;
    int t = blockIdx.x >> 2;
    int qt = 0, c0 = 0;
    for (int i2 = NQT - 1; i2 >= 0; --i2) {
        int n = (2 * (i2 + 1) + CH_FB - 1) / CH_FB;
        if (t < n) { qt = i2; c0 = t; break; }
        t -= n;
    }
    int nkt   = 2 * (qt + 1);
    int kt_lo = c0 * CH_FB;
    int kt_hi = min(kt_lo + CH_FB, nkt);
    bool single = ((nkt + CH_FB - 1) / CH_FB) == 1;

    int tid = threadIdx.x, w = tid >> 6, lane = tid & 63;
    int lr = lane & 31, lg = lane >> 5;
    int qw = qt * 256 + w * 64;
    const bf16_t* Qb = Qr + (size_t)b * S_LEN * DIM;
    const bf16_t* Kb = Kr + (size_t)b * S_LEN * DIM;
    const bf16_t* Vb = Vt + (size_t)b * DIM * S_LEN;

    bf16x8 qf[2][8];
    #pragma unroll
    for (int qb = 0; qb < 2; ++qb)
        #pragma unroll
        for (int s2 = 0; s2 < 8; ++s2)
            qf[qb][s2] = *(const bf16x8*)(Qb + (size_t)(qw + qb * 32 + lr) * DIM
                                          + s2 * 16 + lg * 8);
    f32x16 acc[2][4];
    #pragma unroll
    for (int qb = 0; qb < 2; ++qb)
        #pragma unroll
        for (int db = 0; db < 4; ++db)
            #pragma unroll
            for (int r = 0; r < 16; ++r) acc[qb][db][r] = 0.f;

    for (int kt = kt_lo; kt < kt_hi; ++kt) {
        int kbase = kt * 128;
        #pragma unroll
        for (int j = 0; j < 8; ++j) {
            int idx = tid + j * 256;
            int row = idx >> 4, slot = idx & 15;
            u32x4 kd = *(const u32x4*)(Kb + (size_t)(kbase + row) * DIM + slot * 8);
            *(u32x4*)((char*)Kt + swzo(row, slot * 16)) = kd;
            u32x4 vd = *(const u32x4*)(Vb + (size_t)row * S_LEN + kbase + slot * 8);
            *(u32x4*)((char*)Vl + swzo(row, slot * 16)) = vd;
        }
        __syncthreads();
        #pragma unroll
        for (int kb = 0; kb < 4; ++kb) {
            int ksub = kb * 32;
            int kmin = kbase + ksub;
            if (kmin > qw + 63) break;
            bool do0 = (kmin <= qw + 31);
            f32x16 s0, s1;
            #pragma unroll
            for (int r = 0; r < 16; ++r) { s0[r] = 0.f; s1[r] = 0.f; }
            #pragma unroll
            for (int h = 0; h < 2; ++h) {
                bf16x8 af[4];
                #pragma unroll
                for (int s2 = 0; s2 < 4; ++s2)
                    af[s2] = *(const bf16x8*)((const char*)Kt +
                        swzo(ksub + lr, (h * 64 + s2 * 16 + lg * 8) * 2));
                #pragma unroll
                for (int s2 = 0; s2 < 4; ++s2) {
                    if (do0) s0 = MFMA32(af[s2], qf[0][h * 4 + s2], s0);
                    s1 = MFMA32(af[s2], qf[1][h * 4 + s2], s1);
                }
            }
            if (kmin + 31 > qw) {
                #pragma unroll
                for (int r = 0; r < 16; ++r) {
                    int kg = kmin + (r & 3) + ((r >> 2) << 3) + (lg << 2);
                    s0[r] = (kg > qw + lr)      ? 0.f : s0[r];
                    s1[r] = (kg > qw + 32 + lr) ? 0.f : s1[r];
                }
            }
            unsigned int w0[8], w1[8];
            cvt_swap(s0, w0);
            cvt_swap(s1, w1);
            u32x4 t00 = {w0[0], w0[1], w0[2], w0[3]};
            u32x4 t01 = {w0[4], w0[5], w0[6], w0[7]};
            u32x4 t10 = {w1[0], w1[1], w1[2], w1[3]};
            u32x4 t11 = {w1[4], w1[5], w1[6], w1[7]};
            bf16x8 p00 = __builtin_bit_cast(bf16x8, t00);
            bf16x8 p01 = __builtin_bit_cast(bf16x8, t01);
            bf16x8 p10 = __builtin_bit_cast(bf16x8, t10);
            bf16x8 p11 = __builtin_bit_cast(bf16x8, t11);
            #pragma unroll
            for (int db = 0; db < 4; ++db) {
                bf16x8 vb0 = *(const bf16x8*)((const char*)Vl +
                    swzo(db * 32 + lr, (ksub + lg * 8) * 2));
                bf16x8 vb1 = *(const bf16x8*)((const char*)Vl +
                    swzo(db * 32 + lr, (ksub + 16 + lg * 8) * 2));
                if (do0) {
                    acc[0][db] = MFMA32(p00, vb0, acc[0][db]);
                    acc[0][db] = MFMA32(p01, vb1, acc[0][db]);
                }
                acc[1][db] = MFMA32(p10, vb0, acc[1][db]);
                acc[1][db] = MFMA32(p11, vb1, acc[1][db]);
            }
        }
        __syncthreads();
    }
    float* Ob = Out + (size_t)b * S_LEN * DIM;
    #pragma unroll
    for (int qb = 0; qb < 2; ++qb)
        #pragma unroll
        for (int db = 0; db < 4; ++db)
            #pragma unroll
            for (int r = 0; r < 16; ++r) {
                int q = qw + qb * 32 + (r & 3) + ((r >> 2) << 3) + (lg << 2);
                int d = db * 32 + lr;
                float v = acc[qb][db][r];
                float* p = Ob + (size_t)q * DIM + d;
                if (single) *p = v; else atomicAdd(p, v);
            }
}

extern "C" void kernel_launch(void* const* d_in, const int* in_sizes, int n_in,
                              void* d_out, int out_size, void* d_ws, size_t ws_size,
                              hipStream_t stream) {
    const float* Q = (const float*)d_in[0];
    const float* K = (const float*)d_in[1];
    const float* V = (const float*)d_in[2];
    float* Out = (float*)d_out;

    size_t plane  = (size_t)NB * S_LEN * DIM * sizeof(bf16_t);         // 4 MB
    size_t ghalf  = (size_t)NB * NHC * DIM * DIM * sizeof(bf16_t);     // 8 MB
    size_t gpre   = (size_t)NB * NCH * DIM * DIM * sizeof(bf16_t);     // 4 MB
    char* wsb = (char*)d_ws;

    if (ws_size >= 3 * plane + ghalf + gpre) {
        bf16_t* Qr = (bf16_t*)wsb;
        bf16_t* Kr = (bf16_t*)(wsb + plane);
        bf16_t* Vt = (bf16_t*)(wsb + 2 * plane);
        bf16_t* Gh = (bf16_t*)(wsb + 3 * plane);
        bf16_t* Gp = (bf16_t*)(wsb + 3 * plane + ghalf);
        mega_prep_kernel<<<NB * NHC, 256, 0, stream>>>(Q, K, V, Qr, Kr, Vt, Gh);
        stage2_kernel<<<NB * 64, 128, 0, stream>>>(Gh, Gp);
        stage3_kernel<<<NB * NCH * 2, 256, 0, stream>>>(Qr, Kr, Vt, Gp, Out);
    } else if (ws_size >= 3 * plane) {
        bf16_t* Qr = (bf16_t*)wsb;
        bf16_t* Kr = (bf16_t*)(wsb + plane);
        bf16_t* Vt = (bf16_t*)(wsb + 2 * plane);
        hipMemsetAsync(d_out, 0, (size_t)NB * S_LEN * DIM * sizeof(float), stream);
        prep_fb_kernel<<<ROPE_BLKS + TR_BLKS, 256, 0, stream>>>(Q, K, V, Qr, Kr, Vt);
        int chunks = 0;
        for (int i = 0; i < NQT; ++i) chunks += (2 * (i + 1) + CH_FB - 1) / CH_FB;
        attn_fb_kernel<<<NB * chunks, 256, 0, stream>>>(Qr, Kr, Vt, Out);
    }
}